// Round 8
// baseline (1109.361 us; speedup 1.0000x reference)
//
#include <hip/hip_runtime.h>
#include <cfloat>
#include <cmath>

#define B_ 1024
#define D_ 256
#define H_ 512
#define N_ 100000
#define K_ 96
#define C_ 10
#define SAMP 4096      // sample columns for threshold estimation (fp32 sims
                       // overlay candV exactly: B*SAMP*4 == B*CAPC*4)
#define CAPC 4096      // per-row candidate capacity (expected ~2344 survivors)
#define RCAP 15        // gemm_nt MODE5 slots (unused instantiation-wise now)
#define RCAP2 20       // nt2 MODE5: 256-col tile, mean ~6/row/tile, P(>20)~1e-6

typedef __attribute__((ext_vector_type(8))) short bf16x8;
typedef __attribute__((ext_vector_type(4))) float f32x4;

__device__ __forceinline__ float bf2f(ushort h) {
    union { unsigned u; float f; } v; v.u = ((unsigned)h) << 16; return v.f;
}
__device__ __forceinline__ ushort f2bf(float f) {
    union { float f; unsigned u; } v; v.f = f;
    unsigned u = v.u;
    unsigned r = (u + 0x7fffu + ((u >> 16) & 1u)) >> 16;
    return (ushort)r;
}
// monotone fp32 -> u32 (ascending)
__device__ __forceinline__ unsigned f2key(float f) {
    unsigned u = __float_as_uint(f);
    return (u & 0x80000000u) ? ~u : (u | 0x80000000u);
}
// d^2 from raw dot product -- single definition shared by thr_select and the
// fused filter so sample-column recompute is bitwise identical.
__device__ __forceinline__ float d2_of(float acc, float q2, float c2) {
    return fmaxf(fmaf(-2.f, acc, q2 + c2), 0.f);
}

#define GLDS(g, l)                                                            \
    __builtin_amdgcn_global_load_lds(                                         \
        (const __attribute__((address_space(1))) void*)(g),                   \
        (__attribute__((address_space(3))) void*)(l), 16, 0, 0)

#define FENCE() asm volatile("" ::: "memory")

// ---------------------------------------------------------------------------
// fp32 tiled GEMM (tiny fp32 GEMMs: Wc, Wq, fused xe|xk)
// ---------------------------------------------------------------------------
template <int RELU>
__global__ __launch_bounds__(256) void gemm_nn(const float* __restrict__ A,
                                               const float* __restrict__ Bm,
                                               const float* __restrict__ bias,
                                               float* __restrict__ Cm,
                                               int M, int N, int Kd) {
    __shared__ float sA[16][68];
    __shared__ float sB[16][64];
    const int t  = threadIdx.x;
    const int tx = t & 15, ty = t >> 4;
    const int m0 = blockIdx.y * 64;
    const int n0 = blockIdx.x * 64;
    const int lr = t >> 2;
    const int lk = (t & 3) << 2;
    const int bk = t >> 4;
    const int bn = (t & 15) << 2;

    float acc[4][4] = {};
    for (int k0 = 0; k0 < Kd; k0 += 16) {
        float4 av = make_float4(0.f, 0.f, 0.f, 0.f);
        if (m0 + lr < M)
            av = *(const float4*)(A + (size_t)(m0 + lr) * Kd + k0 + lk);
        sA[lk + 0][lr] = av.x; sA[lk + 1][lr] = av.y;
        sA[lk + 2][lr] = av.z; sA[lk + 3][lr] = av.w;
        float4 bv = *(const float4*)(Bm + (size_t)(k0 + bk) * N + n0 + bn);
        *(float4*)&sB[bk][bn] = bv;
        __syncthreads();
#pragma unroll
        for (int kk = 0; kk < 16; ++kk) {
            float4 a4 = *(const float4*)&sA[kk][ty << 2];
            float4 b4 = *(const float4*)&sB[kk][tx << 2];
            float ar[4] = {a4.x, a4.y, a4.z, a4.w};
            float br[4] = {b4.x, b4.y, b4.z, b4.w};
#pragma unroll
            for (int i = 0; i < 4; ++i)
#pragma unroll
                for (int j = 0; j < 4; ++j)
                    acc[i][j] = fmaf(ar[i], br[j], acc[i][j]);
        }
        __syncthreads();
    }
#pragma unroll
    for (int i = 0; i < 4; ++i) {
        int row = m0 + (ty << 2) + i;
        if (row < M) {
            int col = n0 + (tx << 2);
            float b0 = 0.f, b1 = 0.f, b2 = 0.f, b3 = 0.f;
            if (bias) { b0 = bias[col]; b1 = bias[col + 1]; b2 = bias[col + 2]; b3 = bias[col + 3]; }
            float4 o;
            o.x = acc[i][0] + b0; o.y = acc[i][1] + b1;
            o.z = acc[i][2] + b2; o.w = acc[i][3] + b3;
            if (RELU) {
                o.x = fmaxf(o.x, 0.f); o.y = fmaxf(o.y, 0.f);
                o.z = fmaxf(o.z, 0.f); o.w = fmaxf(o.w, 0.f);
            }
            *(float4*)(Cm + (size_t)row * N + col) = o;
        }
    }
}

// ---------------------------------------------------------------------------
// bf16 MFMA NT GEMM, 128x128 tile (kept for small-N GEMMs: xproj, 3a, P, tsum)
// 2-phase counted-vmcnt pipeline (R5-verified).
// MODE 0: out bf16   MODE 2: raw fp32   MODE 4: +bias fp32
// ---------------------------------------------------------------------------
template <int MODE, int SWZ>
__global__ __launch_bounds__(256) void gemm_nt(const ushort* __restrict__ A,
                                               const ushort* __restrict__ Bv,
                                               const float* __restrict__ bias,
                                               void* __restrict__ Cout,
                                               int M, int Nlim, int K,
                                               int ldc, int nvalid, int per) {
    int m0, n0;
    if (SWZ == 0) {
        m0 = blockIdx.y * 128; n0 = blockIdx.x * 128;
    } else {
        int bid = blockIdx.x;
        int xcd = bid & 7, slot = bid >> 3;
        m0 = (slot & 7) * 128;
        n0 = (xcd * per + (slot >> 3)) * 128;
        if (n0 >= nvalid || m0 >= M) return;
    }

    // [2 buf][A 8192 | B 8192]: A at buf*8192, B at 16384 + buf*8192
    __shared__ __align__(16) char smem[32768];
    const int t = threadIdx.x;
    const int lane = t & 63, w = t >> 6;
    const int wm = w & 1, wn = w >> 1;

    f32x4 acc[4][4];
#pragma unroll
    for (int i = 0; i < 4; ++i)
#pragma unroll
        for (int j = 0; j < 4; ++j)
            acc[i][j] = (f32x4){0.f, 0.f, 0.f, 0.f};

    const int la = lane & 15, lk = lane >> 4;
    const int aoff = (wm * 64 + la) * 64 + lk * 16;
    const int boff = (wn * 64 + la) * 64 + lk * 16;
    const int r_ = t >> 2, cc_ = (t & 3);

    auto stage = [&](int k0, int buf) {
#pragma unroll
        for (int q = 0; q < 2; ++q) {
            int r = r_ + q * 64;
            int ar = m0 + r; ar = (ar < M) ? ar : (M - 1);
            GLDS(A + (size_t)ar * K + k0 + cc_ * 8,
                 (char*)smem + buf * 8192 + (q * 256 + t) * 16);
            int br = n0 + r; br = (br < Nlim) ? br : (Nlim - 1);
            GLDS(Bv + (size_t)br * K + k0 + cc_ * 8,
                 (char*)smem + 16384 + buf * 8192 + (q * 256 + t) * 16);
        }
    };

    stage(0, 0);
    int cur = 0;
    for (int k0 = 0; k0 < K; k0 += 32) {
        if (k0 + 32 < K) {
            stage(k0 + 32, cur ^ 1);
            FENCE();
            asm volatile("s_waitcnt vmcnt(4)" ::: "memory");
        } else {
            FENCE();
            asm volatile("s_waitcnt vmcnt(0)" ::: "memory");
        }
        __builtin_amdgcn_s_barrier(); FENCE();

        bf16x8 af[4], bfr[4];
        const char* pA = (const char*)smem + cur * 8192 + aoff;
        const char* pB = (const char*)smem + 16384 + cur * 8192 + boff;
#pragma unroll
        for (int i = 0; i < 4; ++i)
            af[i] = *(const bf16x8*)(pA + i * 1024);
#pragma unroll
        for (int j = 0; j < 4; ++j)
            bfr[j] = *(const bf16x8*)(pB + j * 1024);
#pragma unroll
        for (int i = 0; i < 4; ++i)
#pragma unroll
            for (int j = 0; j < 4; ++j)
                acc[i][j] = __builtin_amdgcn_mfma_f32_16x16x32_bf16(
                    af[i], bfr[j], acc[i][j], 0, 0, 0);

        FENCE();
        asm volatile("s_waitcnt lgkmcnt(0)" ::: "memory");
        __builtin_amdgcn_s_barrier(); FENCE();
        cur ^= 1;
    }

    const int rl = (lane >> 4) * 4, cl = lane & 15;

#pragma unroll
    for (int i = 0; i < 4; ++i) {
#pragma unroll
        for (int j = 0; j < 4; ++j) {
            int gc = n0 + wn * 64 + j * 16 + cl;
#pragma unroll
            for (int v = 0; v < 4; ++v) {
                int gr = m0 + wm * 64 + i * 16 + rl + v;
                if (gr < M && gc < nvalid) {
                    float val = acc[i][j][v];
                    if (MODE == 2) {
                        ((float*)Cout)[(size_t)gr * ldc + gc] = val;
                    } else if (MODE == 4) {
                        ((float*)Cout)[(size_t)gr * ldc + gc] = val + bias[gc];
                    } else {
                        ((ushort*)Cout)[(size_t)gr * ldc + gc] = f2bf(val);
                    }
                }
            }
        }
    }
}

// ---------------------------------------------------------------------------
// nt2: 128M x 256N tile, 4 waves (each 64M x 128N: acc[4][8]), same 2-phase
// counted-vmcnt pipeline (vmcnt(6): 6 GLDS/thread/step). 32 MFMA per wave per
// K-step (2x gemm_nt) -> per-output barrier cost halves; block count halves.
// Per-output-element accumulation order identical to gemm_nt (ascending 32-k
// MFMA chain) -> d2 bitwise-consistent with thr_select.
// LDS: A 2x8KB + B 2x16KB = 48KB -> >=2 blocks/CU (VGPR-capped).
// SWZ=1: 8 M-tiles (M==1024) x per N-groups/XCD, N-tile 256 (stage 3b).
// SWZ=2: 2 N-tiles (Nlim==512) x per M-groups/XCD, M-tile 128 (c2, Q).
// MODE 3: +bias, out bf16 (Q)
// MODE 5: fused sim filter -> candV/candI append
// MODE 7: c2-only: ||bf16(acc+bias)||^2 per row -> atomicAdd c2 (candV arg)
// ---------------------------------------------------------------------------
template <int MODE, int SWZ>
__global__ __launch_bounds__(256) void gemm_nt2(const ushort* __restrict__ A,
                                                const ushort* __restrict__ Bv,
                                                const float* __restrict__ bias,
                                                const float* __restrict__ q2v,
                                                const float* __restrict__ c2v,
                                                const float* __restrict__ thrv,
                                                float* __restrict__ candV,
                                                int* __restrict__ candI,
                                                int* __restrict__ cnt,
                                                void* __restrict__ Cout,
                                                int M, int Nlim, int K,
                                                int ldc, int nvalid, int per) {
    int m0, n0;
    {
        int bid = blockIdx.x;
        int xcd = bid & 7, slot = bid >> 3;
        if (SWZ == 1) {
            m0 = (slot & 7) * 128;
            n0 = (xcd * per + (slot >> 3)) * 256;
            if (n0 >= nvalid) return;
        } else {
            n0 = (slot & 1) * 256;
            m0 = (xcd * per + (slot >> 1)) * 128;
            if (m0 >= M) return;
        }
    }

    // smem: A buf0 [0,8K) buf1 [8K,16K); B buf0 [16K,32K) buf1 [32K,48K)
    __shared__ __align__(16) char smem[49152];
    const int t = threadIdx.x;
    const int lane = t & 63, w = t >> 6;
    const int wm = w & 1, wn = w >> 1;

    f32x4 acc[4][8];
#pragma unroll
    for (int i = 0; i < 4; ++i)
#pragma unroll
        for (int j = 0; j < 8; ++j)
            acc[i][j] = (f32x4){0.f, 0.f, 0.f, 0.f};

    const int la = lane & 15, lk = lane >> 4;
    const int aoff = (wm * 64 + la) * 64 + lk * 16;
    const int boff = (wn * 128 + la) * 64 + lk * 16;
    const int r_ = t >> 2, cc_ = (t & 3);

    auto stage = [&](int k0, int buf) {
#pragma unroll
        for (int q = 0; q < 2; ++q) {
            int r = r_ + q * 64;
            int ar = m0 + r; ar = (ar < M) ? ar : (M - 1);
            GLDS(A + (size_t)ar * K + k0 + cc_ * 8,
                 (char*)smem + buf * 8192 + (q * 256 + t) * 16);
        }
#pragma unroll
        for (int q = 0; q < 4; ++q) {
            int r = r_ + q * 64;
            int br = n0 + r; br = (br < Nlim) ? br : (Nlim - 1);
            GLDS(Bv + (size_t)br * K + k0 + cc_ * 8,
                 (char*)smem + 16384 + buf * 16384 + (q * 256 + t) * 16);
        }
    };

    stage(0, 0);
    int cur = 0;
    for (int k0 = 0; k0 < K; k0 += 32) {
        if (k0 + 32 < K) {
            stage(k0 + 32, cur ^ 1);
            FENCE();
            asm volatile("s_waitcnt vmcnt(6)" ::: "memory");  // cur's 6 oldest
        } else {
            FENCE();
            asm volatile("s_waitcnt vmcnt(0)" ::: "memory");
        }
        __builtin_amdgcn_s_barrier(); FENCE();

        bf16x8 af[4], bfr[8];
        const char* pA = (const char*)smem + cur * 8192 + aoff;
        const char* pB = (const char*)smem + 16384 + cur * 16384 + boff;
#pragma unroll
        for (int i = 0; i < 4; ++i)
            af[i] = *(const bf16x8*)(pA + i * 1024);
#pragma unroll
        for (int j = 0; j < 8; ++j)
            bfr[j] = *(const bf16x8*)(pB + j * 1024);
#pragma unroll
        for (int i = 0; i < 4; ++i)
#pragma unroll
            for (int j = 0; j < 8; ++j)
                acc[i][j] = __builtin_amdgcn_mfma_f32_16x16x32_bf16(
                    af[i], bfr[j], acc[i][j], 0, 0, 0);

        FENCE();
        asm volatile("s_waitcnt lgkmcnt(0)" ::: "memory");
        __builtin_amdgcn_s_barrier(); FENCE();
        cur ^= 1;
    }

    const int rl = lk * 4, cl = la;

    if (MODE == 7) {
        // per-row ||.||^2 of bf16-rounded (acc+bias) over this wave's 128 cols
#pragma unroll
        for (int i = 0; i < 4; ++i) {
#pragma unroll
            for (int v = 0; v < 4; ++v) {
                int gr = m0 + wm * 64 + i * 16 + rl + v;
                float s = 0.f;
#pragma unroll
                for (int j = 0; j < 8; ++j) {
                    int gc = n0 + wn * 128 + j * 16 + cl;
                    float val = acc[i][j][v] + bias[gc];
                    float vb = bf2f(f2bf(val));
                    s = fmaf(vb, vb, s);
                }
                s += __shfl_xor(s, 1);
                s += __shfl_xor(s, 2);
                s += __shfl_xor(s, 4);
                s += __shfl_xor(s, 8);
                if (cl == 0 && gr < M) atomicAdd(&candV[gr], s);
            }
        }
        return;
    }

    if (MODE == 5) {
        // smem dead after final barrier -- reuse as survivor staging.
        float* stV = (float*)smem;                    // [128][RCAP2]
        int*   stI = (int*)(smem + 128 * RCAP2 * 4);  // [128][RCAP2]
        int*   stC = (int*)(smem + 128 * RCAP2 * 8);  // [128]
        for (int r = t; r < 128; r += 256) stC[r] = 0;
        __syncthreads();
#pragma unroll
        for (int i = 0; i < 4; ++i) {
#pragma unroll
            for (int v = 0; v < 4; ++v) {
                int rloc = wm * 64 + i * 16 + rl + v;
                int gr = m0 + rloc;
                float q2b = q2v[gr];
                float th = thrv[gr];
#pragma unroll
                for (int j = 0; j < 8; ++j) {
                    int gc = n0 + wn * 128 + j * 16 + cl;
                    if (gc < nvalid) {
                        float d2 = d2_of(acc[i][j][v], q2b, c2v[gc]);
                        if (d2 <= th) {
                            int p = atomicAdd(&stC[rloc], 1);
                            if (p < RCAP2) {
                                stV[rloc * RCAP2 + p] = d2;
                                stI[rloc * RCAP2 + p] = gc;
                            } else {
                                // rare overflow: direct global append (exact)
                                int gp = atomicAdd(&cnt[gr], 1);
                                if (gp < CAPC) {
                                    candV[(size_t)gr * CAPC + gp] = d2;
                                    candI[(size_t)gr * CAPC + gp] = gc;
                                }
                            }
                        }
                    }
                }
            }
        }
        __syncthreads();
        for (int r = t; r < 128; r += 256) {
            int n = stC[r]; if (n > RCAP2) n = RCAP2;
            if (n > 0) {
                int gr = m0 + r;
                int gb = atomicAdd(&cnt[gr], n);
                for (int q = 0; q < n; ++q) {
                    int pos = gb + q;
                    if (pos < CAPC) {
                        candV[(size_t)gr * CAPC + pos] = stV[r * RCAP2 + q];
                        candI[(size_t)gr * CAPC + pos] = stI[r * RCAP2 + q];
                    }
                }
            }
        }
        return;
    }

    // MODE 3: +bias, bf16 out
#pragma unroll
    for (int i = 0; i < 4; ++i) {
#pragma unroll
        for (int j = 0; j < 8; ++j) {
            int gc = n0 + wn * 128 + j * 16 + cl;
#pragma unroll
            for (int v = 0; v < 4; ++v) {
                int gr = m0 + wm * 64 + i * 16 + rl + v;
                if (gr < M && gc < nvalid) {
                    float val = acc[i][j][v] + bias[gc];
                    ((ushort*)Cout)[(size_t)gr * ldc + gc] = f2bf(val);
                }
            }
        }
    }
}

// ---------------------------------------------------------------------------
// per-row radix-select of the 96th-SMALLEST d^2 over the first SAMP columns.
// ---------------------------------------------------------------------------
__global__ __launch_bounds__(256) void thr_select(const float* __restrict__ S,
                                                  int ld,
                                                  const float* __restrict__ q2v,
                                                  const float* __restrict__ c2v,
                                                  float* __restrict__ thrArr) {
    __shared__ unsigned keys[SAMP];
    __shared__ int hist[256];
    __shared__ int sel[2];
    const int b = blockIdx.x, t = threadIdx.x;
    const float q2b = q2v[b];
    for (int i = t; i < SAMP; i += 256)
        keys[i] = ~f2key(d2_of(S[(size_t)b * ld + i], q2b, c2v[i]));
    __syncthreads();
    unsigned prefix = 0, mask = 0;
    int rank = K_;
    for (int shift = 24; shift >= 0; shift -= 8) {
        hist[t & 255] = 0;
        __syncthreads();
        for (int i = t; i < SAMP; i += 256) {
            unsigned k = keys[i];
            if ((k & mask) == prefix) atomicAdd(&hist[(k >> shift) & 255], 1);
        }
        __syncthreads();
        if (t == 0) {
            int r = rank, d = 255;
            for (; d > 0; --d) { int c = hist[d]; if (r - c <= 0) break; r -= c; }
            sel[0] = d; sel[1] = (r < 1) ? 1 : r;
        }
        __syncthreads();
        prefix |= ((unsigned)sel[0]) << shift;
        rank = sel[1];
        mask |= (0xFFu << shift);
        __syncthreads();
    }
    if (t == 0) {
        unsigned key = ~prefix;
        thrArr[b] = __uint_as_float(key & 0x7FFFFFFFu);
    }
}

// ---------------------------------------------------------------------------
// per-row exact 96-smallest-d2 from candidate buffer via radix select
// (inverted keys) + compaction. topV receives d2.
// ---------------------------------------------------------------------------
__global__ __launch_bounds__(256) void final_select(const float* __restrict__ candV,
                                                    const int* __restrict__ candI,
                                                    const int* __restrict__ cnt,
                                                    float* __restrict__ topV,
                                                    int* __restrict__ topI) {
    __shared__ unsigned keys[CAPC];
    __shared__ int hist[256];
    __shared__ int sel[2];
    __shared__ int poscnt, eqcnt;
    const int b = blockIdx.x, t = threadIdx.x;
    int n = cnt[b]; if (n > CAPC) n = CAPC;
    for (int i = t; i < n; i += 256)
        keys[i] = ~f2key(candV[(size_t)b * CAPC + i]);
    __syncthreads();
    unsigned prefix = 0, mask = 0;
    int rank = K_;
    for (int shift = 24; shift >= 0; shift -= 8) {
        hist[t & 255] = 0;
        __syncthreads();
        for (int i = t; i < n; i += 256) {
            unsigned k = keys[i];
            if ((k & mask) == prefix) atomicAdd(&hist[(k >> shift) & 255], 1);
        }
        __syncthreads();
        if (t == 0) {
            int r = rank, d = 255;
            for (; d > 0; --d) { int c = hist[d]; if (r - c <= 0) break; r -= c; }
            sel[0] = d; sel[1] = (r < 1) ? 1 : r;
        }
        __syncthreads();
        prefix |= ((unsigned)sel[0]) << shift;
        rank = sel[1];
        mask |= (0xFFu << shift);
        __syncthreads();
    }
    unsigned kth = prefix;
    if (t == 0) { poscnt = 0; eqcnt = 0; }
    __syncthreads();
    for (int i = t; i < n; i += 256) {
        if (keys[i] > kth) {
            int p = atomicAdd(&poscnt, 1);
            topV[b * K_ + p] = candV[(size_t)b * CAPC + i];
            topI[b * K_ + p] = candI[(size_t)b * CAPC + i];
        }
    }
    __syncthreads();
    int base = poscnt;
    for (int i = t; i < n; i += 256) {
        if (keys[i] == kth) {
            int p = atomicAdd(&eqcnt, 1);
            if (base + p < K_) {
                topV[b * K_ + base + p] = candV[(size_t)b * CAPC + i];
                topI[b * K_ + base + p] = candI[(size_t)b * CAPC + i];
            }
        }
    }
}

__global__ void init_cnt(int* cnt) {
    int i = blockIdx.x * 256 + threadIdx.x;
    if (i < B_) cnt[i] = 0;
}

__global__ void init_f32(float* p, int n) {
    int i = blockIdx.x * 256 + threadIdx.x;
    int stride = gridDim.x * 256;
    for (; i < n; i += stride) p[i] = 0.f;
}

// ---------------------------------------------------------------------------
__global__ void conv_f2b(const float* __restrict__ in, ushort* __restrict__ out, int n) {
    int i = (blockIdx.x * 256 + threadIdx.x) * 4;
    int stride = gridDim.x * 256 * 4;
    for (; i < n; i += stride) {
        float4 v = *(const float4*)(in + i);
        ushort4 o;
        o.x = f2bf(v.x); o.y = f2bf(v.y); o.z = f2bf(v.z); o.w = f2bf(v.w);
        *(ushort4*)(out + i) = o;
    }
}

// strided conv: out[r][0..H) = bf16(in[r*ldin + 0..H))  (xk view of xekk)
__global__ void conv_f2b_s(const float* __restrict__ in, ushort* __restrict__ out,
                           int ldin) {
    int i = (blockIdx.x * 256 + threadIdx.x) * 4;
    int stride = gridDim.x * 256 * 4;
    int total = B_ * H_;
    for (; i < total; i += stride) {
        int r = i >> 9, c = i & 511;     // H_ = 512
        float4 v = *(const float4*)(in + (size_t)r * ldin + c);
        ushort4 o;
        o.x = f2bf(v.x); o.y = f2bf(v.y); o.z = f2bf(v.z); o.w = f2bf(v.w);
        *(ushort4*)(out + i) = o;
    }
}

__global__ __launch_bounds__(256) void transpose_f2b(const float* __restrict__ in,
                                                     ushort* __restrict__ out,
                                                     int R, int Cn) {
    __shared__ float tile[32][33];
    int bx = blockIdx.x * 32, by = blockIdx.y * 32;
    int tx = threadIdx.x & 31, ty = threadIdx.x >> 5;
    int x = bx + tx;
#pragma unroll
    for (int dy = 0; dy < 32; dy += 8) {
        int y = by + ty + dy;
        if (x < Cn && y < R) tile[ty + dy][tx] = in[(size_t)y * Cn + x];
    }
    __syncthreads();
    int ox = by + tx;
#pragma unroll
    for (int dy = 0; dy < 32; dy += 8) {
        int oy = bx + ty + dy;
        if (ox < R && oy < Cn) out[(size_t)oy * R + ox] = f2bf(tile[tx][ty + dy]);
    }
}

// pack Wxx = [W_enc | Wc] (fp32 [D,1024]) and bxx = [b_enc ; bc]
__global__ void pack_wxx(const float* __restrict__ W_enc,
                         const float* __restrict__ Wc,
                         const float* __restrict__ b_enc,
                         const float* __restrict__ bc,
                         float* __restrict__ Wxx, float* __restrict__ bxx) {
    int i = blockIdx.x * 256 + threadIdx.x;
    if (i < D_ * H_) {
        int k = i >> 9, h = i & 511;
        Wxx[(size_t)k * 1024 + h] = W_enc[i];
        Wxx[(size_t)k * 1024 + 512 + h] = Wc[i];
    }
    if (i < H_) { bxx[i] = b_enc[i]; bxx[512 + i] = bc[i]; }
}

// q2x[b] = ||xkb[b,:]||^2 - 2 * dot(xk[b,:], bc)   (xk = Xf strided view)
__global__ __launch_bounds__(64) void q2x_k(const ushort* __restrict__ Xb,
                                            const float* __restrict__ Xf,
                                            int ldx,
                                            const float* __restrict__ bc,
                                            float* __restrict__ outv) {
    const int r = blockIdx.x, t = threadIdx.x;
    const ushort* p  = Xb + (size_t)r * H_ + t * 8;
    const float*  xf = Xf + (size_t)r * ldx + t * 8;
    float nrm = 0.f, dot = 0.f;
#pragma unroll
    for (int j = 0; j < 8; ++j) {
        float v = bf2f(p[j]);
        nrm = fmaf(v, v, nrm);
        dot = fmaf(xf[j], bc[t * 8 + j], dot);
    }
    for (int off = 32; off > 0; off >>= 1) {
        nrm += __shfl_down(nrm, off);
        dot += __shfl_down(dot, off);
    }
    if (t == 0) outv[r] = nrm - 2.f * dot;
}

__global__ void bcomb_k(const float* __restrict__ b_enc,
                        const float* __restrict__ W_key,
                        const float* __restrict__ b_key,
                        float* __restrict__ b_comb) {
    int h = blockIdx.x * 256 + threadIdx.x;
    if (h >= H_) return;
    float acc = b_key[h];
    for (int m = 0; m < H_; ++m)
        acc = fmaf(b_enc[m], W_key[(size_t)m * H_ + h], acc);
    b_comb[h] = acc;
}

// bq[h] = sum_m bc[m] * W1[m,h]
__global__ void bq_k(const float* __restrict__ bc,
                     const float* __restrict__ W1,
                     float* __restrict__ bq) {
    int h = blockIdx.x * 256 + threadIdx.x;
    if (h >= H_) return;
    float acc = 0.f;
    for (int m = 0; m < H_; ++m)
        acc = fmaf(bc[m], W1[(size_t)m * H_ + h], acc);
    bq[h] = acc;
}

__global__ __launch_bounds__(128) void softmax_k(const float* __restrict__ topVal,
                                                 float* __restrict__ attn) {
    __shared__ float red[128];
    const int b = blockIdx.x, t = threadIdx.x;
    float v = (t < K_) ? -sqrtf(topVal[b * K_ + t]) : -FLT_MAX;
    red[t] = v; __syncthreads();
    for (int s = 64; s > 0; s >>= 1) {
        if (t < s) red[t] = fmaxf(red[t], red[t + s]);
        __syncthreads();
    }
    float m = red[0]; __syncthreads();
    float e = (t < K_) ? expf(v - m) : 0.f;
    red[t] = e; __syncthreads();
    for (int s = 64; s > 0; s >>= 1) {
        if (t < s) red[t] += red[t + s];
        __syncthreads();
    }
    float ssum = red[0];
    if (t < K_) attn[b * K_ + t] = e / ssum;
}

// ---------------------------------------------------------------------------
// Stage-4 factorized: hw[b,:] = sum_k attn[b,k]*relu(P[b,:]-Q[topI[b,k],:])
// ---------------------------------------------------------------------------
__global__ __launch_bounds__(256) void wsum_q(const float* __restrict__ attn,
                                              const int* __restrict__ topI,
                                              const float* __restrict__ P,
                                              const ushort* __restrict__ Q,
                                              ushort* __restrict__ hw) {
    __shared__ float aw[K_];
    __shared__ int ai[K_];
    const int b = blockIdx.x, t = threadIdx.x;
    if (t < K_) { aw[t] = attn[b * K_ + t]; ai[t] = topI[b * K_ + t]; }
    __syncthreads();
    const float p0 = P[(size_t)b * H_ + 2 * t];
    const float p1 = P[(size_t)b * H_ + 2 * t + 1];
    float a0 = 0.f, a1 = 0.f;
    for (int k = 0; k < K_; ++k) {
        float w = aw[k];
        ushort2 q = *(const ushort2*)(Q + (size_t)ai[k] * H_ + 2 * t);
        a0 = fmaf(w, fmaxf(p0 - bf2f(q.x), 0.f), a0);
        a1 = fmaf(w, fmaxf(p1 - bf2f(q.y), 0.f), a1);
    }
    ushort2 o; o.x = f2bf(a0); o.y = f2bf(a1);
    *(ushort2*)(hw + (size_t)b * H_ + 2 * t) = o;
}

// out = xe + sum_k attn*E[label[topI]] + tsum   (xe = strided view of xekk)
__global__ __launch_bounds__(256) void final_out(const float* __restrict__ attn,
                                                 const int* __restrict__ topI,
                                                 const int* __restrict__ labels,
                                                 const float* __restrict__ E,
                                                 const float* __restrict__ tsum,
                                                 const float* __restrict__ xe,
                                                 int ldxe,
                                                 float* __restrict__ out) {
    const int b = blockIdx.x, t = threadIdx.x;
    float a0 = 0.f, a1 = 0.f;
    for (int k = 0; k < K_; ++k) {
        float w = attn[b * K_ + k];
        int idx = topI[b * K_ + k];
        int lab = labels[idx];
        const float* el = E + (size_t)lab * H_;
        a0 = fmaf(w, el[t], a0);
        a1 = fmaf(w, el[t + 256], a1);
    }
    out[(size_t)b * H_ + t] =
        xe[(size_t)b * ldxe + t] + a0 + tsum[(size_t)b * H_ + t];
    out[(size_t)b * H_ + t + 256] =
        xe[(size_t)b * ldxe + t + 256] + a1 + tsum[(size_t)b * H_ + t + 256];
}

// ---------------------------------------------------------------------------
extern "C" void kernel_launch(void* const* d_in, const int* in_sizes, int n_in,
                              void* d_out, int out_size, void* d_ws, size_t ws_size,
                              hipStream_t stream) {
    const float* x      = (const float*)d_in[0];
    const float* cx     = (const float*)d_in[1];
    const int*   labels = (const int*)d_in[2];
    const float* W_enc  = (const float*)d_in[3];
    const float* b_enc  = (const float*)d_in[4];
    const float* W_key  = (const float*)d_in[5];
    const float* b_key  = (const float*)d_in[6];
    // d_in[7]=W_val, d_in[8]=b_val dead (gather unused in reference)
    const float* E_label = (const float*)d_in[9];
    const float* W_t1   = (const float*)d_in[10];
    const float* b_t1   = (const float*)d_in[11];
    const float* W_t2   = (const float*)d_in[12];
    float* out = (float*)d_out;

    char* base = (char*)d_ws;
    size_t off = 0;
    auto take = [&](size_t n) -> char* {
        char* p = base + off;
        off = (off + n + 255) & ~(size_t)255;
        return p;
    };
    float*  Wc    = (float*)take((size_t)D_ * H_ * 4);
    float*  bc    = (float*)take((size_t)H_ * 4);
    float*  Wxx   = (float*)take((size_t)D_ * 1024 * 4);  // [W_enc | Wc] fp32
    float*  bxx   = (float*)take((size_t)1024 * 4);
    ushort* WcT   = (ushort*)take((size_t)H_ * D_ * 2);
    ushort* Wcb   = (ushort*)take((size_t)D_ * H_ * 2);   // Wc bf16 [D,H]
    float*  Wq    = (float*)take((size_t)D_ * H_ * 4);    // Wc @ W_t1, fp32
    ushort* WqT   = (ushort*)take((size_t)H_ * D_ * 2);   // Wq^T bf16 [H,D]
    float*  bq    = (float*)take((size_t)H_ * 4);         // bc @ W_t1
    ushort* Wt1T  = (ushort*)take((size_t)H_ * H_ * 2);
    ushort* Wt2T  = (ushort*)take((size_t)H_ * H_ * 2);
    float*  xekk  = (float*)take((size_t)B_ * 1024 * 4);  // [xe | xk] fp32
    ushort* xkb   = (ushort*)take((size_t)B_ * H_ * 2);
    ushort* xprojb= (ushort*)take((size_t)B_ * D_ * 2);   // xk @ Wc^T, bf16
    float*  q2x   = (float*)take((size_t)B_ * 4);
    float*  c2    = (float*)take((size_t)N_ * 4);
    float*  topV  = (float*)take((size_t)B_ * K_ * 4);
    int*    topI  = (int*)take((size_t)B_ * K_ * 4);
    float*  thr   = (float*)take((size_t)B_ * 4);
    float*  attn  = (float*)take((size_t)B_ * K_ * 4);
    int*    cnt   = (int*)take((size_t)B_ * 4);
    float*  candV = (float*)take((size_t)B_ * CAPC * 4);
    int*    candI = (int*)take((size_t)B_ * CAPC * 4);
    ushort* hwAll = (ushort*)take((size_t)B_ * H_ * 2);
    float*  tsum  = (float*)take((size_t)B_ * H_ * 4);
    float*  Pbuf  = (float*)take((size_t)B_ * H_ * 4);    // xk@W1+b1, fp32
    ushort* Qb    = (ushort*)take((size_t)N_ * H_ * 2);   // cx@Wq+bq, bf16
    char*   big   = base + off;

    ushort* cxb = (ushort*)big;       // N*D*2 = 51.2 MB
    float* simSmall = (float*)candV;  // B*SAMP*4 overlays candV (dead before 3b)

    const float* xeView = xekk;           // cols 0..511
    const float* xkView = xekk + 512;     // cols 512..1023 (stride 1024)

    // stage 0: combined weights + Q-weights + transposed bf16 weights
    {
        dim3 g(H_ / 64, D_ / 64);
        gemm_nn<0><<<g, 256, 0, stream>>>(W_enc, W_key, nullptr, Wc, D_, H_, H_);
        bcomb_k<<<(H_ + 255) / 256, 256, 0, stream>>>(b_enc, W_key, b_key, bc);
        gemm_nn<0><<<g, 256, 0, stream>>>(Wc, W_t1, nullptr, Wq, D_, H_, H_);
        bq_k<<<(H_ + 255) / 256, 256, 0, stream>>>(bc, W_t1, bq);
        pack_wxx<<<(D_ * H_ + 255) / 256, 256, 0, stream>>>(W_enc, Wc, b_enc,
                                                            bc, Wxx, bxx);
        dim3 gt1((H_ + 31) / 32, (D_ + 31) / 32);
        transpose_f2b<<<gt1, 256, 0, stream>>>(Wc, WcT, D_, H_);
        transpose_f2b<<<gt1, 256, 0, stream>>>(Wq, WqT, D_, H_);
        conv_f2b<<<128, 256, 0, stream>>>(Wc, Wcb, D_ * H_);
        dim3 gt2((H_ + 31) / 32, (H_ + 31) / 32);
        transpose_f2b<<<gt2, 256, 0, stream>>>(W_t1, Wt1T, H_, H_);
        transpose_f2b<<<gt2, 256, 0, stream>>>(W_t2, Wt2T, H_, H_);
    }
    // stage 1: fused query encodes [xe|xk] + bf16 conversions + xproj + P
    {
        dim3 gx(1024 / 64, B_ / 64);         // (16, 16) = 256 blocks
        gemm_nn<0><<<gx, 256, 0, stream>>>(x, Wxx, bxx, xekk, B_, 1024, D_);
        conv_f2b_s<<<1024, 256, 0, stream>>>(xkView, xkb, 1024);
        conv_f2b<<<2048, 256, 0, stream>>>(cx, cxb, N_ * D_);
        // xproj[B,D] = xkb @ Wcb^T (contract over H), bf16 out
        dim3 gp(D_ / 128, B_ / 128);         // (2, 8)
        gemm_nt<0, 0><<<gp, 256, 0, stream>>>(
            xkb, Wcb, nullptr, xprojb, B_, D_, H_, D_, D_, 0);
        q2x_k<<<B_, 64, 0, stream>>>(xkb, xkView, 1024, bc, q2x);
        // P[B,H] = xkb @ W_t1 + b_t1, fp32 out (MODE 4)
        dim3 gq(H_ / 128, B_ / 128);         // (4, 8)
        gemm_nt<4, 0><<<gq, 256, 0, stream>>>(
            xkb, Wt1T, b_t1, Pbuf, B_, H_, H_, H_, H_, 0);
    }
    // stage 2: candidate-key row norms c2 ONLY (nt2 MODE 7, 128x256 tile)
    init_f32<<<128, 256, 0, stream>>>(c2, N_);
    {
        int mt = (N_ + 127) / 128;           // 782
        int mper = (mt + 7) / 8;             // 98
        gemm_nt2<7, 2><<<8 * mper * 2, 256, 0, stream>>>(
            cxb, WcT, bc, nullptr, nullptr, nullptr, c2, nullptr, nullptr,
            nullptr, N_, H_, D_, H_, H_, mper);
    }
    // stage 3a: sample sim GEMM over D-contraction (first SAMP cols, raw dot)
    {
        int nper = (SAMP / 128 + 7) / 8;     // 4
        gemm_nt<2, 1><<<64 * nper, 256, 0, stream>>>(
            xprojb, cxb, nullptr, simSmall, B_, N_, D_, SAMP, SAMP, nper);
        thr_select<<<B_, 256, 0, stream>>>(simSmall, SAMP, q2x, c2, thr);
    }
    // stage 3b: fused sim GEMM + filter (nt2 MODE 5, 128x256 tile)
    init_cnt<<<(B_ + 255) / 256, 256, 0, stream>>>(cnt);
    {
        int NT = (N_ + 255) / 256;           // 391
        int nper = (NT + 7) / 8;             // 49
        gemm_nt2<5, 1><<<64 * nper, 256, 0, stream>>>(
            xprojb, cxb, nullptr, q2x, c2, thr, candV, candI, cnt,
            nullptr, B_, N_, D_, 0, N_, nper);
    }
    // Q[N,H] = cxb @ WqT^T + bq  (nt2 MODE 3, 128x256 tile)
    {
        int mt = (N_ + 127) / 128;           // 782
        int mper = (mt + 7) / 8;             // 98
        gemm_nt2<3, 2><<<8 * mper * 2, 256, 0, stream>>>(
            cxb, WqT, bq, nullptr, nullptr, nullptr, nullptr, nullptr,
            nullptr, Qb, N_, H_, D_, H_, H_, mper);
    }
    final_select<<<B_, 256, 0, stream>>>(candV, candI, cnt, topV, topI);
    softmax_k<<<B_, 128, 0, stream>>>(topV, attn);

    // stage 4: hw = sum_k attn*relu(P-Q[topI]); tsum = hw@W2; out = ...
    wsum_q<<<B_, 256, 0, stream>>>(attn, topI, Pbuf, Qb, hwAll);
    {   // tsum[1024,512] = hwAll @ Wt2T^T (fp32 out via MODE 2)
        dim3 g(H_ / 128, B_ / 128);          // (4, 8)
        gemm_nt<2, 0><<<g, 256, 0, stream>>>(
            hwAll, Wt2T, nullptr, tsum, B_, H_, H_, H_, H_, 0);
    }
    final_out<<<B_, 256, 0, stream>>>(attn, topI, labels, E_label, tsum,
                                      xeView, 1024, out);
}

// Round 9
// 964.879 us; speedup vs baseline: 1.1497x; 1.1497x over previous
//
#include <hip/hip_runtime.h>
#include <cfloat>
#include <cmath>

#define B_ 1024
#define D_ 256
#define H_ 512
#define N_ 100000
#define K_ 96
#define C_ 10
#define SAMP 4096      // sample columns for threshold estimation (fp32 sims
                       // overlay candV exactly: B*SAMP*4 == B*CAPC*4)
#define CAPC 4096      // per-row candidate capacity (expected ~2344 survivors)
#define RCAP2 20       // nt2 MODE5: 256-col tile, mean ~6/row/tile, P(>20)~1e-6

typedef __attribute__((ext_vector_type(8))) short bf16x8;
typedef __attribute__((ext_vector_type(4))) float f32x4;

__device__ __forceinline__ float bf2f(ushort h) {
    union { unsigned u; float f; } v; v.u = ((unsigned)h) << 16; return v.f;
}
__device__ __forceinline__ ushort f2bf(float f) {
    union { float f; unsigned u; } v; v.f = f;
    unsigned u = v.u;
    unsigned r = (u + 0x7fffu + ((u >> 16) & 1u)) >> 16;
    return (ushort)r;
}
// monotone fp32 -> u32 (ascending)
__device__ __forceinline__ unsigned f2key(float f) {
    unsigned u = __float_as_uint(f);
    return (u & 0x80000000u) ? ~u : (u | 0x80000000u);
}
// d^2 from raw dot product -- single definition shared by thr_select and the
// fused filter so sample-column recompute is bitwise identical.
__device__ __forceinline__ float d2_of(float acc, float q2, float c2) {
    return fmaxf(fmaf(-2.f, acc, q2 + c2), 0.f);
}

#define GLDS(g, l)                                                            \
    __builtin_amdgcn_global_load_lds(                                         \
        (const __attribute__((address_space(1))) void*)(g),                   \
        (__attribute__((address_space(3))) void*)(l), 16, 0, 0)

#define FENCE() asm volatile("" ::: "memory")

// ---------------------------------------------------------------------------
// fp32 tiled GEMM (tiny fp32 GEMMs: Wc, Wq, fused xe|xk)
// ---------------------------------------------------------------------------
template <int RELU>
__global__ __launch_bounds__(256) void gemm_nn(const float* __restrict__ A,
                                               const float* __restrict__ Bm,
                                               const float* __restrict__ bias,
                                               float* __restrict__ Cm,
                                               int M, int N, int Kd) {
    __shared__ float sA[16][68];
    __shared__ float sB[16][64];
    const int t  = threadIdx.x;
    const int tx = t & 15, ty = t >> 4;
    const int m0 = blockIdx.y * 64;
    const int n0 = blockIdx.x * 64;
    const int lr = t >> 2;
    const int lk = (t & 3) << 2;
    const int bk = t >> 4;
    const int bn = (t & 15) << 2;

    float acc[4][4] = {};
    for (int k0 = 0; k0 < Kd; k0 += 16) {
        float4 av = make_float4(0.f, 0.f, 0.f, 0.f);
        if (m0 + lr < M)
            av = *(const float4*)(A + (size_t)(m0 + lr) * Kd + k0 + lk);
        sA[lk + 0][lr] = av.x; sA[lk + 1][lr] = av.y;
        sA[lk + 2][lr] = av.z; sA[lk + 3][lr] = av.w;
        float4 bv = *(const float4*)(Bm + (size_t)(k0 + bk) * N + n0 + bn);
        *(float4*)&sB[bk][bn] = bv;
        __syncthreads();
#pragma unroll
        for (int kk = 0; kk < 16; ++kk) {
            float4 a4 = *(const float4*)&sA[kk][ty << 2];
            float4 b4 = *(const float4*)&sB[kk][tx << 2];
            float ar[4] = {a4.x, a4.y, a4.z, a4.w};
            float br[4] = {b4.x, b4.y, b4.z, b4.w};
#pragma unroll
            for (int i = 0; i < 4; ++i)
#pragma unroll
                for (int j = 0; j < 4; ++j)
                    acc[i][j] = fmaf(ar[i], br[j], acc[i][j]);
        }
        __syncthreads();
    }
#pragma unroll
    for (int i = 0; i < 4; ++i) {
        int row = m0 + (ty << 2) + i;
        if (row < M) {
            int col = n0 + (tx << 2);
            float b0 = 0.f, b1 = 0.f, b2 = 0.f, b3 = 0.f;
            if (bias) { b0 = bias[col]; b1 = bias[col + 1]; b2 = bias[col + 2]; b3 = bias[col + 3]; }
            float4 o;
            o.x = acc[i][0] + b0; o.y = acc[i][1] + b1;
            o.z = acc[i][2] + b2; o.w = acc[i][3] + b3;
            if (RELU) {
                o.x = fmaxf(o.x, 0.f); o.y = fmaxf(o.y, 0.f);
                o.z = fmaxf(o.z, 0.f); o.w = fmaxf(o.w, 0.f);
            }
            *(float4*)(Cm + (size_t)row * N + col) = o;
        }
    }
}

// ---------------------------------------------------------------------------
// bf16 MFMA NT GEMM, 128x128 tile (kept for small-N GEMMs: xproj, 3a, P, tsum)
// 2-phase counted-vmcnt pipeline (R5-verified).
// MODE 0: out bf16   MODE 2: raw fp32   MODE 4: +bias fp32
// ---------------------------------------------------------------------------
template <int MODE, int SWZ>
__global__ __launch_bounds__(256) void gemm_nt(const ushort* __restrict__ A,
                                               const ushort* __restrict__ Bv,
                                               const float* __restrict__ bias,
                                               void* __restrict__ Cout,
                                               int M, int Nlim, int K,
                                               int ldc, int nvalid, int per) {
    int m0, n0;
    if (SWZ == 0) {
        m0 = blockIdx.y * 128; n0 = blockIdx.x * 128;
    } else {
        int bid = blockIdx.x;
        int xcd = bid & 7, slot = bid >> 3;
        m0 = (slot & 7) * 128;
        n0 = (xcd * per + (slot >> 3)) * 128;
        if (n0 >= nvalid || m0 >= M) return;
    }

    // [2 buf][A 8192 | B 8192]: A at buf*8192, B at 16384 + buf*8192
    __shared__ __align__(16) char smem[32768];
    const int t = threadIdx.x;
    const int lane = t & 63, w = t >> 6;
    const int wm = w & 1, wn = w >> 1;

    f32x4 acc[4][4];
#pragma unroll
    for (int i = 0; i < 4; ++i)
#pragma unroll
        for (int j = 0; j < 4; ++j)
            acc[i][j] = (f32x4){0.f, 0.f, 0.f, 0.f};

    const int la = lane & 15, lk = lane >> 4;
    const int aoff = (wm * 64 + la) * 64 + lk * 16;
    const int boff = (wn * 64 + la) * 64 + lk * 16;
    const int r_ = t >> 2, cc_ = (t & 3);

    auto stage = [&](int k0, int buf) {
#pragma unroll
        for (int q = 0; q < 2; ++q) {
            int r = r_ + q * 64;
            int ar = m0 + r; ar = (ar < M) ? ar : (M - 1);
            GLDS(A + (size_t)ar * K + k0 + cc_ * 8,
                 (char*)smem + buf * 8192 + (q * 256 + t) * 16);
            int br = n0 + r; br = (br < Nlim) ? br : (Nlim - 1);
            GLDS(Bv + (size_t)br * K + k0 + cc_ * 8,
                 (char*)smem + 16384 + buf * 8192 + (q * 256 + t) * 16);
        }
    };

    stage(0, 0);
    int cur = 0;
    for (int k0 = 0; k0 < K; k0 += 32) {
        if (k0 + 32 < K) {
            stage(k0 + 32, cur ^ 1);
            FENCE();
            asm volatile("s_waitcnt vmcnt(4)" ::: "memory");
        } else {
            FENCE();
            asm volatile("s_waitcnt vmcnt(0)" ::: "memory");
        }
        __builtin_amdgcn_s_barrier(); FENCE();

        bf16x8 af[4], bfr[4];
        const char* pA = (const char*)smem + cur * 8192 + aoff;
        const char* pB = (const char*)smem + 16384 + cur * 8192 + boff;
#pragma unroll
        for (int i = 0; i < 4; ++i)
            af[i] = *(const bf16x8*)(pA + i * 1024);
#pragma unroll
        for (int j = 0; j < 4; ++j)
            bfr[j] = *(const bf16x8*)(pB + j * 1024);
#pragma unroll
        for (int i = 0; i < 4; ++i)
#pragma unroll
            for (int j = 0; j < 4; ++j)
                acc[i][j] = __builtin_amdgcn_mfma_f32_16x16x32_bf16(
                    af[i], bfr[j], acc[i][j], 0, 0, 0);

        FENCE();
        asm volatile("s_waitcnt lgkmcnt(0)" ::: "memory");
        __builtin_amdgcn_s_barrier(); FENCE();
        cur ^= 1;
    }

    const int rl = (lane >> 4) * 4, cl = lane & 15;

#pragma unroll
    for (int i = 0; i < 4; ++i) {
#pragma unroll
        for (int j = 0; j < 4; ++j) {
            int gc = n0 + wn * 64 + j * 16 + cl;
#pragma unroll
            for (int v = 0; v < 4; ++v) {
                int gr = m0 + wm * 64 + i * 16 + rl + v;
                if (gr < M && gc < nvalid) {
                    float val = acc[i][j][v];
                    if (MODE == 2) {
                        ((float*)Cout)[(size_t)gr * ldc + gc] = val;
                    } else if (MODE == 4) {
                        ((float*)Cout)[(size_t)gr * ldc + gc] = val + bias[gc];
                    } else {
                        ((ushort*)Cout)[(size_t)gr * ldc + gc] = f2bf(val);
                    }
                }
            }
        }
    }
}

// ---------------------------------------------------------------------------
// nt2: 128M x 256N tile, 4 waves (each 64M x 128N: acc[4][8]), same 2-phase
// counted-vmcnt pipeline (vmcnt(6): 6 GLDS/thread/step). 32 MFMA per wave per
// K-step (2x gemm_nt) -> per-output barrier cost halves; block count halves.
// R8 LESSON: without an explicit min-waves hint the allocator capped VGPR at
// 140 (< the ~176 live: acc 128 + frags 48) and SPILLED acc to scratch ->
// 2x regression. __launch_bounds__(256, 2) caps occupancy at 2 waves/EU
// (= 2 blocks/CU, 8 waves/CU) -> VGPR budget 256/wave -> no spill.
// Per-output-element accumulation order identical to gemm_nt (ascending 32-k
// MFMA chain) -> d2 bitwise-consistent with thr_select.
// LDS: A 2x8KB + B 2x16KB = 48KB.
// SWZ=1: 8 M-tiles (M==1024) x per N-groups/XCD, N-tile 256 (stage 3b).
// SWZ=2: 2 N-tiles (Nlim==512) x per M-groups/XCD, M-tile 128 (c2, Q).
// MODE 3: +bias, out bf16 (Q)
// MODE 5: fused sim filter -> candV/candI append
// MODE 7: c2-only: ||bf16(acc+bias)||^2 per row -> atomicAdd c2 (candV arg)
// ---------------------------------------------------------------------------
template <int MODE, int SWZ>
__global__ __launch_bounds__(256, 2) void gemm_nt2(const ushort* __restrict__ A,
                                                   const ushort* __restrict__ Bv,
                                                   const float* __restrict__ bias,
                                                   const float* __restrict__ q2v,
                                                   const float* __restrict__ c2v,
                                                   const float* __restrict__ thrv,
                                                   float* __restrict__ candV,
                                                   int* __restrict__ candI,
                                                   int* __restrict__ cnt,
                                                   void* __restrict__ Cout,
                                                   int M, int Nlim, int K,
                                                   int ldc, int nvalid, int per) {
    int m0, n0;
    {
        int bid = blockIdx.x;
        int xcd = bid & 7, slot = bid >> 3;
        if (SWZ == 1) {
            m0 = (slot & 7) * 128;
            n0 = (xcd * per + (slot >> 3)) * 256;
            if (n0 >= nvalid) return;
        } else {
            n0 = (slot & 1) * 256;
            m0 = (xcd * per + (slot >> 1)) * 128;
            if (m0 >= M) return;
        }
    }

    // smem: A buf0 [0,8K) buf1 [8K,16K); B buf0 [16K,32K) buf1 [32K,48K)
    __shared__ __align__(16) char smem[49152];
    const int t = threadIdx.x;
    const int lane = t & 63, w = t >> 6;
    const int wm = w & 1, wn = w >> 1;

    f32x4 acc[4][8];
#pragma unroll
    for (int i = 0; i < 4; ++i)
#pragma unroll
        for (int j = 0; j < 8; ++j)
            acc[i][j] = (f32x4){0.f, 0.f, 0.f, 0.f};

    const int la = lane & 15, lk = lane >> 4;
    const int aoff = (wm * 64 + la) * 64 + lk * 16;
    const int boff = (wn * 128 + la) * 64 + lk * 16;
    const int r_ = t >> 2, cc_ = (t & 3);

    auto stage = [&](int k0, int buf) {
#pragma unroll
        for (int q = 0; q < 2; ++q) {
            int r = r_ + q * 64;
            int ar = m0 + r; ar = (ar < M) ? ar : (M - 1);
            GLDS(A + (size_t)ar * K + k0 + cc_ * 8,
                 (char*)smem + buf * 8192 + (q * 256 + t) * 16);
        }
#pragma unroll
        for (int q = 0; q < 4; ++q) {
            int r = r_ + q * 64;
            int br = n0 + r; br = (br < Nlim) ? br : (Nlim - 1);
            GLDS(Bv + (size_t)br * K + k0 + cc_ * 8,
                 (char*)smem + 16384 + buf * 16384 + (q * 256 + t) * 16);
        }
    };

    stage(0, 0);
    int cur = 0;
    for (int k0 = 0; k0 < K; k0 += 32) {
        if (k0 + 32 < K) {
            stage(k0 + 32, cur ^ 1);
            FENCE();
            asm volatile("s_waitcnt vmcnt(6)" ::: "memory");  // cur's 6 oldest
        } else {
            FENCE();
            asm volatile("s_waitcnt vmcnt(0)" ::: "memory");
        }
        __builtin_amdgcn_s_barrier(); FENCE();

        bf16x8 af[4], bfr[8];
        const char* pA = (const char*)smem + cur * 8192 + aoff;
        const char* pB = (const char*)smem + 16384 + cur * 16384 + boff;
#pragma unroll
        for (int i = 0; i < 4; ++i)
            af[i] = *(const bf16x8*)(pA + i * 1024);
#pragma unroll
        for (int j = 0; j < 8; ++j)
            bfr[j] = *(const bf16x8*)(pB + j * 1024);
#pragma unroll
        for (int i = 0; i < 4; ++i)
#pragma unroll
            for (int j = 0; j < 8; ++j)
                acc[i][j] = __builtin_amdgcn_mfma_f32_16x16x32_bf16(
                    af[i], bfr[j], acc[i][j], 0, 0, 0);

        FENCE();
        asm volatile("s_waitcnt lgkmcnt(0)" ::: "memory");
        __builtin_amdgcn_s_barrier(); FENCE();
        cur ^= 1;
    }

    const int rl = lk * 4, cl = la;

    if (MODE == 7) {
        // per-row ||.||^2 of bf16-rounded (acc+bias) over this wave's 128 cols
#pragma unroll
        for (int i = 0; i < 4; ++i) {
#pragma unroll
            for (int v = 0; v < 4; ++v) {
                int gr = m0 + wm * 64 + i * 16 + rl + v;
                float s = 0.f;
#pragma unroll
                for (int j = 0; j < 8; ++j) {
                    int gc = n0 + wn * 128 + j * 16 + cl;
                    float val = acc[i][j][v] + bias[gc];
                    float vb = bf2f(f2bf(val));
                    s = fmaf(vb, vb, s);
                }
                s += __shfl_xor(s, 1);
                s += __shfl_xor(s, 2);
                s += __shfl_xor(s, 4);
                s += __shfl_xor(s, 8);
                if (cl == 0 && gr < M) atomicAdd(&candV[gr], s);
            }
        }
        return;
    }

    if (MODE == 5) {
        // smem dead after final barrier -- reuse as survivor staging.
        float* stV = (float*)smem;                    // [128][RCAP2]
        int*   stI = (int*)(smem + 128 * RCAP2 * 4);  // [128][RCAP2]
        int*   stC = (int*)(smem + 128 * RCAP2 * 8);  // [128]
        for (int r = t; r < 128; r += 256) stC[r] = 0;
        __syncthreads();
#pragma unroll
        for (int i = 0; i < 4; ++i) {
#pragma unroll
            for (int v = 0; v < 4; ++v) {
                int rloc = wm * 64 + i * 16 + rl + v;
                int gr = m0 + rloc;
                float q2b = q2v[gr];
                float th = thrv[gr];
#pragma unroll
                for (int j = 0; j < 8; ++j) {
                    int gc = n0 + wn * 128 + j * 16 + cl;
                    if (gc < nvalid) {
                        float d2 = d2_of(acc[i][j][v], q2b, c2v[gc]);
                        if (d2 <= th) {
                            int p = atomicAdd(&stC[rloc], 1);
                            if (p < RCAP2) {
                                stV[rloc * RCAP2 + p] = d2;
                                stI[rloc * RCAP2 + p] = gc;
                            } else {
                                // rare overflow: direct global append (exact)
                                int gp = atomicAdd(&cnt[gr], 1);
                                if (gp < CAPC) {
                                    candV[(size_t)gr * CAPC + gp] = d2;
                                    candI[(size_t)gr * CAPC + gp] = gc;
                                }
                            }
                        }
                    }
                }
            }
        }
        __syncthreads();
        for (int r = t; r < 128; r += 256) {
            int n = stC[r]; if (n > RCAP2) n = RCAP2;
            if (n > 0) {
                int gr = m0 + r;
                int gb = atomicAdd(&cnt[gr], n);
                for (int q = 0; q < n; ++q) {
                    int pos = gb + q;
                    if (pos < CAPC) {
                        candV[(size_t)gr * CAPC + pos] = stV[r * RCAP2 + q];
                        candI[(size_t)gr * CAPC + pos] = stI[r * RCAP2 + q];
                    }
                }
            }
        }
        return;
    }

    // MODE 3: +bias, bf16 out
#pragma unroll
    for (int i = 0; i < 4; ++i) {
#pragma unroll
        for (int j = 0; j < 8; ++j) {
            int gc = n0 + wn * 128 + j * 16 + cl;
#pragma unroll
            for (int v = 0; v < 4; ++v) {
                int gr = m0 + wm * 64 + i * 16 + rl + v;
                if (gr < M && gc < nvalid) {
                    float val = acc[i][j][v] + bias[gc];
                    ((ushort*)Cout)[(size_t)gr * ldc + gc] = f2bf(val);
                }
            }
        }
    }
}

// ---------------------------------------------------------------------------
// per-row radix-select of the 96th-SMALLEST d^2 over the first SAMP columns.
// ---------------------------------------------------------------------------
__global__ __launch_bounds__(256) void thr_select(const float* __restrict__ S,
                                                  int ld,
                                                  const float* __restrict__ q2v,
                                                  const float* __restrict__ c2v,
                                                  float* __restrict__ thrArr) {
    __shared__ unsigned keys[SAMP];
    __shared__ int hist[256];
    __shared__ int sel[2];
    const int b = blockIdx.x, t = threadIdx.x;
    const float q2b = q2v[b];
    for (int i = t; i < SAMP; i += 256)
        keys[i] = ~f2key(d2_of(S[(size_t)b * ld + i], q2b, c2v[i]));
    __syncthreads();
    unsigned prefix = 0, mask = 0;
    int rank = K_;
    for (int shift = 24; shift >= 0; shift -= 8) {
        hist[t & 255] = 0;
        __syncthreads();
        for (int i = t; i < SAMP; i += 256) {
            unsigned k = keys[i];
            if ((k & mask) == prefix) atomicAdd(&hist[(k >> shift) & 255], 1);
        }
        __syncthreads();
        if (t == 0) {
            int r = rank, d = 255;
            for (; d > 0; --d) { int c = hist[d]; if (r - c <= 0) break; r -= c; }
            sel[0] = d; sel[1] = (r < 1) ? 1 : r;
        }
        __syncthreads();
        prefix |= ((unsigned)sel[0]) << shift;
        rank = sel[1];
        mask |= (0xFFu << shift);
        __syncthreads();
    }
    if (t == 0) {
        unsigned key = ~prefix;
        thrArr[b] = __uint_as_float(key & 0x7FFFFFFFu);
    }
}

// ---------------------------------------------------------------------------
// per-row exact 96-smallest-d2 from candidate buffer via radix select
// (inverted keys) + compaction. topV receives d2.
// ---------------------------------------------------------------------------
__global__ __launch_bounds__(256) void final_select(const float* __restrict__ candV,
                                                    const int* __restrict__ candI,
                                                    const int* __restrict__ cnt,
                                                    float* __restrict__ topV,
                                                    int* __restrict__ topI) {
    __shared__ unsigned keys[CAPC];
    __shared__ int hist[256];
    __shared__ int sel[2];
    __shared__ int poscnt, eqcnt;
    const int b = blockIdx.x, t = threadIdx.x;
    int n = cnt[b]; if (n > CAPC) n = CAPC;
    for (int i = t; i < n; i += 256)
        keys[i] = ~f2key(candV[(size_t)b * CAPC + i]);
    __syncthreads();
    unsigned prefix = 0, mask = 0;
    int rank = K_;
    for (int shift = 24; shift >= 0; shift -= 8) {
        hist[t & 255] = 0;
        __syncthreads();
        for (int i = t; i < n; i += 256) {
            unsigned k = keys[i];
            if ((k & mask) == prefix) atomicAdd(&hist[(k >> shift) & 255], 1);
        }
        __syncthreads();
        if (t == 0) {
            int r = rank, d = 255;
            for (; d > 0; --d) { int c = hist[d]; if (r - c <= 0) break; r -= c; }
            sel[0] = d; sel[1] = (r < 1) ? 1 : r;
        }
        __syncthreads();
        prefix |= ((unsigned)sel[0]) << shift;
        rank = sel[1];
        mask |= (0xFFu << shift);
        __syncthreads();
    }
    unsigned kth = prefix;
    if (t == 0) { poscnt = 0; eqcnt = 0; }
    __syncthreads();
    for (int i = t; i < n; i += 256) {
        if (keys[i] > kth) {
            int p = atomicAdd(&poscnt, 1);
            topV[b * K_ + p] = candV[(size_t)b * CAPC + i];
            topI[b * K_ + p] = candI[(size_t)b * CAPC + i];
        }
    }
    __syncthreads();
    int base = poscnt;
    for (int i = t; i < n; i += 256) {
        if (keys[i] == kth) {
            int p = atomicAdd(&eqcnt, 1);
            if (base + p < K_) {
                topV[b * K_ + base + p] = candV[(size_t)b * CAPC + i];
                topI[b * K_ + base + p] = candI[(size_t)b * CAPC + i];
            }
        }
    }
}

__global__ void init_cnt(int* cnt) {
    int i = blockIdx.x * 256 + threadIdx.x;
    if (i < B_) cnt[i] = 0;
}

__global__ void init_f32(float* p, int n) {
    int i = blockIdx.x * 256 + threadIdx.x;
    int stride = gridDim.x * 256;
    for (; i < n; i += stride) p[i] = 0.f;
}

// ---------------------------------------------------------------------------
__global__ void conv_f2b(const float* __restrict__ in, ushort* __restrict__ out, int n) {
    int i = (blockIdx.x * 256 + threadIdx.x) * 4;
    int stride = gridDim.x * 256 * 4;
    for (; i < n; i += stride) {
        float4 v = *(const float4*)(in + i);
        ushort4 o;
        o.x = f2bf(v.x); o.y = f2bf(v.y); o.z = f2bf(v.z); o.w = f2bf(v.w);
        *(ushort4*)(out + i) = o;
    }
}

// strided conv: out[r][0..H) = bf16(in[r*ldin + 0..H))  (xk view of xekk)
__global__ void conv_f2b_s(const float* __restrict__ in, ushort* __restrict__ out,
                           int ldin) {
    int i = (blockIdx.x * 256 + threadIdx.x) * 4;
    int stride = gridDim.x * 256 * 4;
    int total = B_ * H_;
    for (; i < total; i += stride) {
        int r = i >> 9, c = i & 511;     // H_ = 512
        float4 v = *(const float4*)(in + (size_t)r * ldin + c);
        ushort4 o;
        o.x = f2bf(v.x); o.y = f2bf(v.y); o.z = f2bf(v.z); o.w = f2bf(v.w);
        *(ushort4*)(out + i) = o;
    }
}

__global__ __launch_bounds__(256) void transpose_f2b(const float* __restrict__ in,
                                                     ushort* __restrict__ out,
                                                     int R, int Cn) {
    __shared__ float tile[32][33];
    int bx = blockIdx.x * 32, by = blockIdx.y * 32;
    int tx = threadIdx.x & 31, ty = threadIdx.x >> 5;
    int x = bx + tx;
#pragma unroll
    for (int dy = 0; dy < 32; dy += 8) {
        int y = by + ty + dy;
        if (x < Cn && y < R) tile[ty + dy][tx] = in[(size_t)y * Cn + x];
    }
    __syncthreads();
    int ox = by + tx;
#pragma unroll
    for (int dy = 0; dy < 32; dy += 8) {
        int oy = bx + ty + dy;
        if (ox < R && oy < Cn) out[(size_t)oy * R + ox] = f2bf(tile[tx][ty + dy]);
    }
}

// pack Wxx = [W_enc | Wc] (fp32 [D,1024]) and bxx = [b_enc ; bc]
__global__ void pack_wxx(const float* __restrict__ W_enc,
                         const float* __restrict__ Wc,
                         const float* __restrict__ b_enc,
                         const float* __restrict__ bc,
                         float* __restrict__ Wxx, float* __restrict__ bxx) {
    int i = blockIdx.x * 256 + threadIdx.x;
    if (i < D_ * H_) {
        int k = i >> 9, h = i & 511;
        Wxx[(size_t)k * 1024 + h] = W_enc[i];
        Wxx[(size_t)k * 1024 + 512 + h] = Wc[i];
    }
    if (i < H_) { bxx[i] = b_enc[i]; bxx[512 + i] = bc[i]; }
}

// q2x[b] = ||xkb[b,:]||^2 - 2 * dot(xk[b,:], bc)   (xk = Xf strided view)
__global__ __launch_bounds__(64) void q2x_k(const ushort* __restrict__ Xb,
                                            const float* __restrict__ Xf,
                                            int ldx,
                                            const float* __restrict__ bc,
                                            float* __restrict__ outv) {
    const int r = blockIdx.x, t = threadIdx.x;
    const ushort* p  = Xb + (size_t)r * H_ + t * 8;
    const float*  xf = Xf + (size_t)r * ldx + t * 8;
    float nrm = 0.f, dot = 0.f;
#pragma unroll
    for (int j = 0; j < 8; ++j) {
        float v = bf2f(p[j]);
        nrm = fmaf(v, v, nrm);
        dot = fmaf(xf[j], bc[t * 8 + j], dot);
    }
    for (int off = 32; off > 0; off >>= 1) {
        nrm += __shfl_down(nrm, off);
        dot += __shfl_down(dot, off);
    }
    if (t == 0) outv[r] = nrm - 2.f * dot;
}

__global__ void bcomb_k(const float* __restrict__ b_enc,
                        const float* __restrict__ W_key,
                        const float* __restrict__ b_key,
                        float* __restrict__ b_comb) {
    int h = blockIdx.x * 256 + threadIdx.x;
    if (h >= H_) return;
    float acc = b_key[h];
    for (int m = 0; m < H_; ++m)
        acc = fmaf(b_enc[m], W_key[(size_t)m * H_ + h], acc);
    b_comb[h] = acc;
}

// bq[h] = sum_m bc[m] * W1[m,h]
__global__ void bq_k(const float* __restrict__ bc,
                     const float* __restrict__ W1,
                     float* __restrict__ bq) {
    int h = blockIdx.x * 256 + threadIdx.x;
    if (h >= H_) return;
    float acc = 0.f;
    for (int m = 0; m < H_; ++m)
        acc = fmaf(bc[m], W1[(size_t)m * H_ + h], acc);
    bq[h] = acc;
}

__global__ __launch_bounds__(128) void softmax_k(const float* __restrict__ topVal,
                                                 float* __restrict__ attn) {
    __shared__ float red[128];
    const int b = blockIdx.x, t = threadIdx.x;
    float v = (t < K_) ? -sqrtf(topVal[b * K_ + t]) : -FLT_MAX;
    red[t] = v; __syncthreads();
    for (int s = 64; s > 0; s >>= 1) {
        if (t < s) red[t] = fmaxf(red[t], red[t + s]);
        __syncthreads();
    }
    float m = red[0]; __syncthreads();
    float e = (t < K_) ? expf(v - m) : 0.f;
    red[t] = e; __syncthreads();
    for (int s = 64; s > 0; s >>= 1) {
        if (t < s) red[t] += red[t + s];
        __syncthreads();
    }
    float ssum = red[0];
    if (t < K_) attn[b * K_ + t] = e / ssum;
}

// ---------------------------------------------------------------------------
// Stage-4 factorized: hw[b,:] = sum_k attn[b,k]*relu(P[b,:]-Q[topI[b,k],:])
// ---------------------------------------------------------------------------
__global__ __launch_bounds__(256) void wsum_q(const float* __restrict__ attn,
                                              const int* __restrict__ topI,
                                              const float* __restrict__ P,
                                              const ushort* __restrict__ Q,
                                              ushort* __restrict__ hw) {
    __shared__ float aw[K_];
    __shared__ int ai[K_];
    const int b = blockIdx.x, t = threadIdx.x;
    if (t < K_) { aw[t] = attn[b * K_ + t]; ai[t] = topI[b * K_ + t]; }
    __syncthreads();
    const float p0 = P[(size_t)b * H_ + 2 * t];
    const float p1 = P[(size_t)b * H_ + 2 * t + 1];
    float a0 = 0.f, a1 = 0.f;
    for (int k = 0; k < K_; ++k) {
        float w = aw[k];
        ushort2 q = *(const ushort2*)(Q + (size_t)ai[k] * H_ + 2 * t);
        a0 = fmaf(w, fmaxf(p0 - bf2f(q.x), 0.f), a0);
        a1 = fmaf(w, fmaxf(p1 - bf2f(q.y), 0.f), a1);
    }
    ushort2 o; o.x = f2bf(a0); o.y = f2bf(a1);
    *(ushort2*)(hw + (size_t)b * H_ + 2 * t) = o;
}

// out = xe + sum_k attn*E[label[topI]] + tsum   (xe = strided view of xekk)
__global__ __launch_bounds__(256) void final_out(const float* __restrict__ attn,
                                                 const int* __restrict__ topI,
                                                 const int* __restrict__ labels,
                                                 const float* __restrict__ E,
                                                 const float* __restrict__ tsum,
                                                 const float* __restrict__ xe,
                                                 int ldxe,
                                                 float* __restrict__ out) {
    const int b = blockIdx.x, t = threadIdx.x;
    float a0 = 0.f, a1 = 0.f;
    for (int k = 0; k < K_; ++k) {
        float w = attn[b * K_ + k];
        int idx = topI[b * K_ + k];
        int lab = labels[idx];
        const float* el = E + (size_t)lab * H_;
        a0 = fmaf(w, el[t], a0);
        a1 = fmaf(w, el[t + 256], a1);
    }
    out[(size_t)b * H_ + t] =
        xe[(size_t)b * ldxe + t] + a0 + tsum[(size_t)b * H_ + t];
    out[(size_t)b * H_ + t + 256] =
        xe[(size_t)b * ldxe + t + 256] + a1 + tsum[(size_t)b * H_ + t + 256];
}

// ---------------------------------------------------------------------------
extern "C" void kernel_launch(void* const* d_in, const int* in_sizes, int n_in,
                              void* d_out, int out_size, void* d_ws, size_t ws_size,
                              hipStream_t stream) {
    const float* x      = (const float*)d_in[0];
    const float* cx     = (const float*)d_in[1];
    const int*   labels = (const int*)d_in[2];
    const float* W_enc  = (const float*)d_in[3];
    const float* b_enc  = (const float*)d_in[4];
    const float* W_key  = (const float*)d_in[5];
    const float* b_key  = (const float*)d_in[6];
    // d_in[7]=W_val, d_in[8]=b_val dead (gather unused in reference)
    const float* E_label = (const float*)d_in[9];
    const float* W_t1   = (const float*)d_in[10];
    const float* b_t1   = (const float*)d_in[11];
    const float* W_t2   = (const float*)d_in[12];
    float* out = (float*)d_out;

    char* base = (char*)d_ws;
    size_t off = 0;
    auto take = [&](size_t n) -> char* {
        char* p = base + off;
        off = (off + n + 255) & ~(size_t)255;
        return p;
    };
    float*  Wc    = (float*)take((size_t)D_ * H_ * 4);
    float*  bc    = (float*)take((size_t)H_ * 4);
    float*  Wxx   = (float*)take((size_t)D_ * 1024 * 4);  // [W_enc | Wc] fp32
    float*  bxx   = (float*)take((size_t)1024 * 4);
    ushort* WcT   = (ushort*)take((size_t)H_ * D_ * 2);
    ushort* Wcb   = (ushort*)take((size_t)D_ * H_ * 2);   // Wc bf16 [D,H]
    float*  Wq    = (float*)take((size_t)D_ * H_ * 4);    // Wc @ W_t1, fp32
    ushort* WqT   = (ushort*)take((size_t)H_ * D_ * 2);   // Wq^T bf16 [H,D]
    float*  bq    = (float*)take((size_t)H_ * 4);         // bc @ W_t1
    ushort* Wt1T  = (ushort*)take((size_t)H_ * H_ * 2);
    ushort* Wt2T  = (ushort*)take((size_t)H_ * H_ * 2);
    float*  xekk  = (float*)take((size_t)B_ * 1024 * 4);  // [xe | xk] fp32
    ushort* xkb   = (ushort*)take((size_t)B_ * H_ * 2);
    ushort* xprojb= (ushort*)take((size_t)B_ * D_ * 2);   // xk @ Wc^T, bf16
    float*  q2x   = (float*)take((size_t)B_ * 4);
    float*  c2    = (float*)take((size_t)N_ * 4);
    float*  topV  = (float*)take((size_t)B_ * K_ * 4);
    int*    topI  = (int*)take((size_t)B_ * K_ * 4);
    float*  thr   = (float*)take((size_t)B_ * 4);
    float*  attn  = (float*)take((size_t)B_ * K_ * 4);
    int*    cnt   = (int*)take((size_t)B_ * 4);
    float*  candV = (float*)take((size_t)B_ * CAPC * 4);
    int*    candI = (int*)take((size_t)B_ * CAPC * 4);
    ushort* hwAll = (ushort*)take((size_t)B_ * H_ * 2);
    float*  tsum  = (float*)take((size_t)B_ * H_ * 4);
    float*  Pbuf  = (float*)take((size_t)B_ * H_ * 4);    // xk@W1+b1, fp32
    ushort* Qb    = (ushort*)take((size_t)N_ * H_ * 2);   // cx@Wq+bq, bf16
    char*   big   = base + off;

    ushort* cxb = (ushort*)big;       // N*D*2 = 51.2 MB
    float* simSmall = (float*)candV;  // B*SAMP*4 overlays candV (dead before 3b)

    const float* xeView = xekk;           // cols 0..511
    const float* xkView = xekk + 512;     // cols 512..1023 (stride 1024)

    // stage 0: combined weights + Q-weights + transposed bf16 weights
    {
        dim3 g(H_ / 64, D_ / 64);
        gemm_nn<0><<<g, 256, 0, stream>>>(W_enc, W_key, nullptr, Wc, D_, H_, H_);
        bcomb_k<<<(H_ + 255) / 256, 256, 0, stream>>>(b_enc, W_key, b_key, bc);
        gemm_nn<0><<<g, 256, 0, stream>>>(Wc, W_t1, nullptr, Wq, D_, H_, H_);
        bq_k<<<(H_ + 255) / 256, 256, 0, stream>>>(bc, W_t1, bq);
        pack_wxx<<<(D_ * H_ + 255) / 256, 256, 0, stream>>>(W_enc, Wc, b_enc,
                                                            bc, Wxx, bxx);
        dim3 gt1((H_ + 31) / 32, (D_ + 31) / 32);
        transpose_f2b<<<gt1, 256, 0, stream>>>(Wc, WcT, D_, H_);
        transpose_f2b<<<gt1, 256, 0, stream>>>(Wq, WqT, D_, H_);
        conv_f2b<<<128, 256, 0, stream>>>(Wc, Wcb, D_ * H_);
        dim3 gt2((H_ + 31) / 32, (H_ + 31) / 32);
        transpose_f2b<<<gt2, 256, 0, stream>>>(W_t1, Wt1T, H_, H_);
        transpose_f2b<<<gt2, 256, 0, stream>>>(W_t2, Wt2T, H_, H_);
    }
    // stage 1: fused query encodes [xe|xk] + bf16 conversions + xproj + P
    {
        dim3 gx(1024 / 64, B_ / 64);         // (16, 16) = 256 blocks
        gemm_nn<0><<<gx, 256, 0, stream>>>(x, Wxx, bxx, xekk, B_, 1024, D_);
        conv_f2b_s<<<1024, 256, 0, stream>>>(xkView, xkb, 1024);
        conv_f2b<<<2048, 256, 0, stream>>>(cx, cxb, N_ * D_);
        // xproj[B,D] = xkb @ Wcb^T (contract over H), bf16 out
        dim3 gp(D_ / 128, B_ / 128);         // (2, 8)
        gemm_nt<0, 0><<<gp, 256, 0, stream>>>(
            xkb, Wcb, nullptr, xprojb, B_, D_, H_, D_, D_, 0);
        q2x_k<<<B_, 64, 0, stream>>>(xkb, xkView, 1024, bc, q2x);
        // P[B,H] = xkb @ W_t1 + b_t1, fp32 out (MODE 4)
        dim3 gq(H_ / 128, B_ / 128);         // (4, 8)
        gemm_nt<4, 0><<<gq, 256, 0, stream>>>(
            xkb, Wt1T, b_t1, Pbuf, B_, H_, H_, H_, H_, 0);
    }
    // stage 2: candidate-key row norms c2 ONLY (nt2 MODE 7, 128x256 tile)
    init_f32<<<128, 256, 0, stream>>>(c2, N_);
    {
        int mt = (N_ + 127) / 128;           // 782
        int mper = (mt + 7) / 8;             // 98
        gemm_nt2<7, 2><<<8 * mper * 2, 256, 0, stream>>>(
            cxb, WcT, bc, nullptr, nullptr, nullptr, c2, nullptr, nullptr,
            nullptr, N_, H_, D_, H_, H_, mper);
    }
    // stage 3a: sample sim GEMM over D-contraction (first SAMP cols, raw dot)
    {
        int nper = (SAMP / 128 + 7) / 8;     // 4
        gemm_nt<2, 1><<<64 * nper, 256, 0, stream>>>(
            xprojb, cxb, nullptr, simSmall, B_, N_, D_, SAMP, SAMP, nper);
        thr_select<<<B_, 256, 0, stream>>>(simSmall, SAMP, q2x, c2, thr);
    }
    // stage 3b: fused sim GEMM + filter (nt2 MODE 5, 128x256 tile)
    init_cnt<<<(B_ + 255) / 256, 256, 0, stream>>>(cnt);
    {
        int NT = (N_ + 255) / 256;           // 391
        int nper = (NT + 7) / 8;             // 49
        gemm_nt2<5, 1><<<64 * nper, 256, 0, stream>>>(
            xprojb, cxb, nullptr, q2x, c2, thr, candV, candI, cnt,
            nullptr, B_, N_, D_, 0, N_, nper);
    }
    // Q[N,H] = cxb @ WqT^T + bq  (nt2 MODE 3, 128x256 tile)
    {
        int mt = (N_ + 127) / 128;           // 782
        int mper = (mt + 7) / 8;             // 98
        gemm_nt2<3, 2><<<8 * mper * 2, 256, 0, stream>>>(
            cxb, WqT, bq, nullptr, nullptr, nullptr, nullptr, nullptr,
            nullptr, Qb, N_, H_, D_, H_, H_, mper);
    }
    final_select<<<B_, 256, 0, stream>>>(candV, candI, cnt, topV, topI);
    softmax_k<<<B_, 128, 0, stream>>>(topV, attn);

    // stage 4: hw = sum_k attn*relu(P-Q[topI]); tsum = hw@W2; out = ...
    wsum_q<<<B_, 256, 0, stream>>>(attn, topI, Pbuf, Qb, hwAll);
    {   // tsum[1024,512] = hwAll @ Wt2T^T (fp32 out via MODE 2)
        dim3 g(H_ / 128, B_ / 128);          // (4, 8)
        gemm_nt<2, 0><<<g, 256, 0, stream>>>(
            hwAll, Wt2T, nullptr, tsum, B_, H_, H_, H_, H_, 0);
    }
    final_out<<<B_, 256, 0, stream>>>(attn, topI, labels, E_label, tsum,
                                      xeView, 1024, out);
}

// Round 10
// 827.028 us; speedup vs baseline: 1.3414x; 1.1667x over previous
//
#include <hip/hip_runtime.h>
#include <cfloat>
#include <cmath>

#define B_ 1024
#define D_ 256
#define H_ 512
#define N_ 100000
#define K_ 96
#define C_ 10
#define SAMP 4096      // sample columns for threshold estimation (fp32 sims
                       // overlay candV exactly: B*SAMP*4 == B*CAPC*4)
#define CAPC 4096      // per-row candidate capacity (expected ~2344 survivors)
#define RCAP 15        // per-row per-tile LDS staging slots (mean ~3/tile;
                       // overflow falls back to direct global append)

typedef __attribute__((ext_vector_type(8))) short bf16x8;
typedef __attribute__((ext_vector_type(4))) float f32x4;

__device__ __forceinline__ float bf2f(ushort h) {
    union { unsigned u; float f; } v; v.u = ((unsigned)h) << 16; return v.f;
}
__device__ __forceinline__ ushort f2bf(float f) {
    union { float f; unsigned u; } v; v.f = f;
    unsigned u = v.u;
    unsigned r = (u + 0x7fffu + ((u >> 16) & 1u)) >> 16;
    return (ushort)r;
}
// monotone fp32 -> u32 (ascending)
__device__ __forceinline__ unsigned f2key(float f) {
    unsigned u = __float_as_uint(f);
    return (u & 0x80000000u) ? ~u : (u | 0x80000000u);
}
// d^2 from raw dot product -- single definition shared by thr_select and the
// fused filter so sample-column recompute is bitwise identical.
__device__ __forceinline__ float d2_of(float acc, float q2, float c2) {
    return fmaxf(fmaf(-2.f, acc, q2 + c2), 0.f);
}

#define GLDS(g, l)                                                            \
    __builtin_amdgcn_global_load_lds(                                         \
        (const __attribute__((address_space(1))) void*)(g),                   \
        (__attribute__((address_space(3))) void*)(l), 16, 0, 0)

#define FENCE() asm volatile("" ::: "memory")

// ---------------------------------------------------------------------------
// fp32 tiled GEMM (tiny fp32 GEMMs: Wc, Wq, fused xe|xk)
// ---------------------------------------------------------------------------
template <int RELU>
__global__ __launch_bounds__(256) void gemm_nn(const float* __restrict__ A,
                                               const float* __restrict__ Bm,
                                               const float* __restrict__ bias,
                                               float* __restrict__ Cm,
                                               int M, int N, int Kd) {
    __shared__ float sA[16][68];
    __shared__ float sB[16][64];
    const int t  = threadIdx.x;
    const int tx = t & 15, ty = t >> 4;
    const int m0 = blockIdx.y * 64;
    const int n0 = blockIdx.x * 64;
    const int lr = t >> 2;
    const int lk = (t & 3) << 2;
    const int bk = t >> 4;
    const int bn = (t & 15) << 2;

    float acc[4][4] = {};
    for (int k0 = 0; k0 < Kd; k0 += 16) {
        float4 av = make_float4(0.f, 0.f, 0.f, 0.f);
        if (m0 + lr < M)
            av = *(const float4*)(A + (size_t)(m0 + lr) * Kd + k0 + lk);
        sA[lk + 0][lr] = av.x; sA[lk + 1][lr] = av.y;
        sA[lk + 2][lr] = av.z; sA[lk + 3][lr] = av.w;
        float4 bv = *(const float4*)(Bm + (size_t)(k0 + bk) * N + n0 + bn);
        *(float4*)&sB[bk][bn] = bv;
        __syncthreads();
#pragma unroll
        for (int kk = 0; kk < 16; ++kk) {
            float4 a4 = *(const float4*)&sA[kk][ty << 2];
            float4 b4 = *(const float4*)&sB[kk][tx << 2];
            float ar[4] = {a4.x, a4.y, a4.z, a4.w};
            float br[4] = {b4.x, b4.y, b4.z, b4.w};
#pragma unroll
            for (int i = 0; i < 4; ++i)
#pragma unroll
                for (int j = 0; j < 4; ++j)
                    acc[i][j] = fmaf(ar[i], br[j], acc[i][j]);
        }
        __syncthreads();
    }
#pragma unroll
    for (int i = 0; i < 4; ++i) {
        int row = m0 + (ty << 2) + i;
        if (row < M) {
            int col = n0 + (tx << 2);
            float b0 = 0.f, b1 = 0.f, b2 = 0.f, b3 = 0.f;
            if (bias) { b0 = bias[col]; b1 = bias[col + 1]; b2 = bias[col + 2]; b3 = bias[col + 3]; }
            float4 o;
            o.x = acc[i][0] + b0; o.y = acc[i][1] + b1;
            o.z = acc[i][2] + b2; o.w = acc[i][3] + b3;
            if (RELU) {
                o.x = fmaxf(o.x, 0.f); o.y = fmaxf(o.y, 0.f);
                o.z = fmaxf(o.z, 0.f); o.w = fmaxf(o.w, 0.f);
            }
            *(float4*)(Cm + (size_t)row * N + col) = o;
        }
    }
}

// ---------------------------------------------------------------------------
// bf16 MFMA NT GEMM: C = epilogue(A[M,K] @ B[N,K]^T)
// 128x128 tile, BK=32, 4 waves, 2-phase counted-vmcnt pipeline (R5-verified;
// R8/R9 lesson: the 128x256 acc[4][8] variant spills regardless of
// launch_bounds -- 128x128 acc[4][4] @ 76 VGPR is the sweet spot).
// MODE 0: out bf16
// MODE 2: raw dot product -> fp32 Cout
// MODE 3: +bias (no relu), out bf16
// MODE 4: +bias (no relu), out fp32
// MODE 5: fused sim filter: d2<=thr[row] survivors staged in reused LDS,
//         per-row batch append to candV/candI (no C written at all)
// MODE 7: c2-only: accumulate ||bf16(acc+bias)||^2 per OUTPUT ROW into
//         c2out (candV arg); NOTHING else written
// ---------------------------------------------------------------------------
template <int MODE, int SWZ>
__global__ __launch_bounds__(256) void gemm_nt(const ushort* __restrict__ A,
                                               const ushort* __restrict__ Bv,
                                               const float* __restrict__ bias,
                                               const float* __restrict__ q2v,
                                               const float* __restrict__ c2v,
                                               const float* __restrict__ thrv,
                                               float* __restrict__ candV,
                                               int* __restrict__ candI,
                                               int* __restrict__ cnt,
                                               void* __restrict__ Cout,
                                               int M, int Nlim, int K,
                                               int ldc, int nvalid, int per) {
    int m0, n0;
    if (SWZ == 0) {
        m0 = blockIdx.y * 128; n0 = blockIdx.x * 128;
    } else if (SWZ == 1) {
        int bid = blockIdx.x;
        int xcd = bid & 7, slot = bid >> 3;
        m0 = (slot & 7) * 128;
        n0 = (xcd * per + (slot >> 3)) * 128;
        if (n0 >= nvalid || m0 >= M) return;
    } else {
        int bid = blockIdx.x;
        int xcd = bid & 7, slot = bid >> 3;
        n0 = (slot & 3) * 128;
        m0 = (xcd * per + (slot >> 2)) * 128;
        if (m0 >= M) return;
    }

    // [2 buf][A 8192 | B 8192]: A at buf*8192, B at 16384 + buf*8192
    __shared__ __align__(16) char smem[32768];
    const int t = threadIdx.x;
    const int lane = t & 63, w = t >> 6;
    const int wm = w & 1, wn = w >> 1;

    f32x4 acc[4][4];
#pragma unroll
    for (int i = 0; i < 4; ++i)
#pragma unroll
        for (int j = 0; j < 4; ++j)
            acc[i][j] = (f32x4){0.f, 0.f, 0.f, 0.f};

    const int la = lane & 15, lk = lane >> 4;
    const int aoff = (wm * 64 + la) * 64 + lk * 16;
    const int boff = (wn * 64 + la) * 64 + lk * 16;
    const int r_ = t >> 2, cc_ = (t & 3);

    auto stage = [&](int k0, int buf) {
#pragma unroll
        for (int q = 0; q < 2; ++q) {
            int r = r_ + q * 64;
            int ar = m0 + r; ar = (ar < M) ? ar : (M - 1);
            GLDS(A + (size_t)ar * K + k0 + cc_ * 8,
                 (char*)smem + buf * 8192 + (q * 256 + t) * 16);
            int br = n0 + r; br = (br < Nlim) ? br : (Nlim - 1);
            GLDS(Bv + (size_t)br * K + k0 + cc_ * 8,
                 (char*)smem + 16384 + buf * 8192 + (q * 256 + t) * 16);
        }
    };

    stage(0, 0);
    int cur = 0;
    for (int k0 = 0; k0 < K; k0 += 32) {
        if (k0 + 32 < K) {
            stage(k0 + 32, cur ^ 1);       // prefetch next step into other buf
            FENCE();
            asm volatile("s_waitcnt vmcnt(4)" ::: "memory");  // cur's 4 oldest
        } else {
            FENCE();
            asm volatile("s_waitcnt vmcnt(0)" ::: "memory");
        }
        __builtin_amdgcn_s_barrier(); FENCE();

        bf16x8 af[4], bfr[4];
        const char* pA = (const char*)smem + cur * 8192 + aoff;
        const char* pB = (const char*)smem + 16384 + cur * 8192 + boff;
#pragma unroll
        for (int i = 0; i < 4; ++i)
            af[i] = *(const bf16x8*)(pA + i * 1024);
#pragma unroll
        for (int j = 0; j < 4; ++j)
            bfr[j] = *(const bf16x8*)(pB + j * 1024);
#pragma unroll
        for (int i = 0; i < 4; ++i)
#pragma unroll
            for (int j = 0; j < 4; ++j)
                acc[i][j] = __builtin_amdgcn_mfma_f32_16x16x32_bf16(
                    af[i], bfr[j], acc[i][j], 0, 0, 0);

        FENCE();
        asm volatile("s_waitcnt lgkmcnt(0)" ::: "memory");  // reads done
        __builtin_amdgcn_s_barrier(); FENCE();              // before overwrite
        cur ^= 1;
    }

    const int rl = (lane >> 4) * 4, cl = lane & 15;

    if (MODE == 7) {
        // per-row ||.||^2 of bf16-rounded (acc+bias): per-thread partial over
        // its 4 cols, shfl-reduce across the 16-lane (la) group, one atomic
        // per row per wave. c2out := candV arg.
#pragma unroll
        for (int i = 0; i < 4; ++i) {
#pragma unroll
            for (int v = 0; v < 4; ++v) {
                int gr = m0 + wm * 64 + i * 16 + rl + v;
                float s = 0.f;
#pragma unroll
                for (int j = 0; j < 4; ++j) {
                    int gc = n0 + wn * 64 + j * 16 + cl;
                    float val = acc[i][j][v] + bias[gc];
                    float vb = bf2f(f2bf(val));
                    s = fmaf(vb, vb, s);
                }
                s += __shfl_xor(s, 1);
                s += __shfl_xor(s, 2);
                s += __shfl_xor(s, 4);
                s += __shfl_xor(s, 8);
                if (cl == 0 && gr < M) atomicAdd(&candV[gr], s);
            }
        }
        return;
    }

    if (MODE == 5) {
        // smem is dead after the final barrier -- reuse as staging.
        float* stV = (float*)smem;               // [128][RCAP] = 7680 B
        int*   stI = (int*)(smem + 7680);        // [128][RCAP] = 7680 B
        int*   stC = (int*)(smem + 15360);       // [128]       =  512 B
        for (int r = t; r < 128; r += 256) stC[r] = 0;
        __syncthreads();
#pragma unroll
        for (int i = 0; i < 4; ++i) {
#pragma unroll
            for (int v = 0; v < 4; ++v) {
                int rloc = wm * 64 + i * 16 + rl + v;
                int gr = m0 + rloc;
                float q2b = q2v[gr];
                float th = thrv[gr];
#pragma unroll
                for (int j = 0; j < 4; ++j) {
                    int gc = n0 + wn * 64 + j * 16 + cl;
                    if (gc < nvalid) {
                        float d2 = d2_of(acc[i][j][v], q2b, c2v[gc]);
                        if (d2 <= th) {
                            int p = atomicAdd(&stC[rloc], 1);
                            if (p < RCAP) {
                                stV[rloc * RCAP + p] = d2;
                                stI[rloc * RCAP + p] = gc;
                            } else {
                                // rare overflow: direct global append (exact)
                                int gp = atomicAdd(&cnt[gr], 1);
                                if (gp < CAPC) {
                                    candV[(size_t)gr * CAPC + gp] = d2;
                                    candI[(size_t)gr * CAPC + gp] = gc;
                                }
                            }
                        }
                    }
                }
            }
        }
        __syncthreads();
        for (int r = t; r < 128; r += 256) {
            int n = stC[r]; if (n > RCAP) n = RCAP;
            if (n > 0) {
                int gr = m0 + r;
                int gb = atomicAdd(&cnt[gr], n);
                for (int q = 0; q < n; ++q) {
                    int pos = gb + q;
                    if (pos < CAPC) {
                        candV[(size_t)gr * CAPC + pos] = stV[r * RCAP + q];
                        candI[(size_t)gr * CAPC + pos] = stI[r * RCAP + q];
                    }
                }
            }
        }
        return;
    }

#pragma unroll
    for (int i = 0; i < 4; ++i) {
#pragma unroll
        for (int j = 0; j < 4; ++j) {
            int gc = n0 + wn * 64 + j * 16 + cl;
#pragma unroll
            for (int v = 0; v < 4; ++v) {
                int gr = m0 + wm * 64 + i * 16 + rl + v;
                if (gr < M && gc < nvalid) {
                    float val = acc[i][j][v];
                    if (MODE == 2) {
                        ((float*)Cout)[(size_t)gr * ldc + gc] = val;
                    } else if (MODE == 4) {
                        ((float*)Cout)[(size_t)gr * ldc + gc] = val + bias[gc];
                    } else {
                        if (MODE == 3) val += bias[gc];
                        ((ushort*)Cout)[(size_t)gr * ldc + gc] = f2bf(val);
                    }
                }
            }
        }
    }
}

// ---------------------------------------------------------------------------
// per-row radix-select of the 96th-SMALLEST d^2 over the first SAMP columns.
// ---------------------------------------------------------------------------
__global__ __launch_bounds__(256) void thr_select(const float* __restrict__ S,
                                                  int ld,
                                                  const float* __restrict__ q2v,
                                                  const float* __restrict__ c2v,
                                                  float* __restrict__ thrArr) {
    __shared__ unsigned keys[SAMP];
    __shared__ int hist[256];
    __shared__ int sel[2];
    const int b = blockIdx.x, t = threadIdx.x;
    const float q2b = q2v[b];
    for (int i = t; i < SAMP; i += 256)
        keys[i] = ~f2key(d2_of(S[(size_t)b * ld + i], q2b, c2v[i]));
    __syncthreads();
    unsigned prefix = 0, mask = 0;
    int rank = K_;
    for (int shift = 24; shift >= 0; shift -= 8) {
        hist[t & 255] = 0;
        __syncthreads();
        for (int i = t; i < SAMP; i += 256) {
            unsigned k = keys[i];
            if ((k & mask) == prefix) atomicAdd(&hist[(k >> shift) & 255], 1);
        }
        __syncthreads();
        if (t == 0) {
            int r = rank, d = 255;
            for (; d > 0; --d) { int c = hist[d]; if (r - c <= 0) break; r -= c; }
            sel[0] = d; sel[1] = (r < 1) ? 1 : r;
        }
        __syncthreads();
        prefix |= ((unsigned)sel[0]) << shift;
        rank = sel[1];
        mask |= (0xFFu << shift);
        __syncthreads();
    }
    if (t == 0) {
        unsigned key = ~prefix;
        thrArr[b] = __uint_as_float(key & 0x7FFFFFFFu);
    }
}

// ---------------------------------------------------------------------------
// per-row exact 96-smallest-d2 from candidate buffer via radix select
// (inverted keys) + compaction. topV receives d2.
// ---------------------------------------------------------------------------
__global__ __launch_bounds__(256) void final_select(const float* __restrict__ candV,
                                                    const int* __restrict__ candI,
                                                    const int* __restrict__ cnt,
                                                    float* __restrict__ topV,
                                                    int* __restrict__ topI) {
    __shared__ unsigned keys[CAPC];
    __shared__ int hist[256];
    __shared__ int sel[2];
    __shared__ int poscnt, eqcnt;
    const int b = blockIdx.x, t = threadIdx.x;
    int n = cnt[b]; if (n > CAPC) n = CAPC;
    for (int i = t; i < n; i += 256)
        keys[i] = ~f2key(candV[(size_t)b * CAPC + i]);
    __syncthreads();
    unsigned prefix = 0, mask = 0;
    int rank = K_;
    for (int shift = 24; shift >= 0; shift -= 8) {
        hist[t & 255] = 0;
        __syncthreads();
        for (int i = t; i < n; i += 256) {
            unsigned k = keys[i];
            if ((k & mask) == prefix) atomicAdd(&hist[(k >> shift) & 255], 1);
        }
        __syncthreads();
        if (t == 0) {
            int r = rank, d = 255;
            for (; d > 0; --d) { int c = hist[d]; if (r - c <= 0) break; r -= c; }
            sel[0] = d; sel[1] = (r < 1) ? 1 : r;
        }
        __syncthreads();
        prefix |= ((unsigned)sel[0]) << shift;
        rank = sel[1];
        mask |= (0xFFu << shift);
        __syncthreads();
    }
    unsigned kth = prefix;
    if (t == 0) { poscnt = 0; eqcnt = 0; }
    __syncthreads();
    for (int i = t; i < n; i += 256) {
        if (keys[i] > kth) {
            int p = atomicAdd(&poscnt, 1);
            topV[b * K_ + p] = candV[(size_t)b * CAPC + i];
            topI[b * K_ + p] = candI[(size_t)b * CAPC + i];
        }
    }
    __syncthreads();
    int base = poscnt;
    for (int i = t; i < n; i += 256) {
        if (keys[i] == kth) {
            int p = atomicAdd(&eqcnt, 1);
            if (base + p < K_) {
                topV[b * K_ + base + p] = candV[(size_t)b * CAPC + i];
                topI[b * K_ + base + p] = candI[(size_t)b * CAPC + i];
            }
        }
    }
}

__global__ void init_cnt(int* cnt) {
    int i = blockIdx.x * 256 + threadIdx.x;
    if (i < B_) cnt[i] = 0;
}

__global__ void init_f32(float* p, int n) {
    int i = blockIdx.x * 256 + threadIdx.x;
    int stride = gridDim.x * 256;
    for (; i < n; i += stride) p[i] = 0.f;
}

// ---------------------------------------------------------------------------
__global__ void conv_f2b(const float* __restrict__ in, ushort* __restrict__ out, int n) {
    int i = (blockIdx.x * 256 + threadIdx.x) * 4;
    int stride = gridDim.x * 256 * 4;
    for (; i < n; i += stride) {
        float4 v = *(const float4*)(in + i);
        ushort4 o;
        o.x = f2bf(v.x); o.y = f2bf(v.y); o.z = f2bf(v.z); o.w = f2bf(v.w);
        *(ushort4*)(out + i) = o;
    }
}

// strided conv: out[r][0..H) = bf16(in[r*ldin + 0..H))  (xk view of xekk)
__global__ void conv_f2b_s(const float* __restrict__ in, ushort* __restrict__ out,
                           int ldin) {
    int i = (blockIdx.x * 256 + threadIdx.x) * 4;
    int stride = gridDim.x * 256 * 4;
    int total = B_ * H_;
    for (; i < total; i += stride) {
        int r = i >> 9, c = i & 511;     // H_ = 512
        float4 v = *(const float4*)(in + (size_t)r * ldin + c);
        ushort4 o;
        o.x = f2bf(v.x); o.y = f2bf(v.y); o.z = f2bf(v.z); o.w = f2bf(v.w);
        *(ushort4*)(out + i) = o;
    }
}

__global__ __launch_bounds__(256) void transpose_f2b(const float* __restrict__ in,
                                                     ushort* __restrict__ out,
                                                     int R, int Cn) {
    __shared__ float tile[32][33];
    int bx = blockIdx.x * 32, by = blockIdx.y * 32;
    int tx = threadIdx.x & 31, ty = threadIdx.x >> 5;
    int x = bx + tx;
#pragma unroll
    for (int dy = 0; dy < 32; dy += 8) {
        int y = by + ty + dy;
        if (x < Cn && y < R) tile[ty + dy][tx] = in[(size_t)y * Cn + x];
    }
    __syncthreads();
    int ox = by + tx;
#pragma unroll
    for (int dy = 0; dy < 32; dy += 8) {
        int oy = bx + ty + dy;
        if (ox < R && oy < Cn) out[(size_t)oy * R + ox] = f2bf(tile[tx][ty + dy]);
    }
}

// pack Wxx = [W_enc | Wc] (fp32 [D,1024]) and bxx = [b_enc ; bc]
__global__ void pack_wxx(const float* __restrict__ W_enc,
                         const float* __restrict__ Wc,
                         const float* __restrict__ b_enc,
                         const float* __restrict__ bc,
                         float* __restrict__ Wxx, float* __restrict__ bxx) {
    int i = blockIdx.x * 256 + threadIdx.x;
    if (i < D_ * H_) {
        int k = i >> 9, h = i & 511;
        Wxx[(size_t)k * 1024 + h] = W_enc[i];
        Wxx[(size_t)k * 1024 + 512 + h] = Wc[i];
    }
    if (i < H_) { bxx[i] = b_enc[i]; bxx[512 + i] = bc[i]; }
}

// q2x[b] = ||xkb[b,:]||^2 - 2 * dot(xk[b,:], bc)   (xk = Xf strided view)
__global__ __launch_bounds__(64) void q2x_k(const ushort* __restrict__ Xb,
                                            const float* __restrict__ Xf,
                                            int ldx,
                                            const float* __restrict__ bc,
                                            float* __restrict__ outv) {
    const int r = blockIdx.x, t = threadIdx.x;
    const ushort* p  = Xb + (size_t)r * H_ + t * 8;
    const float*  xf = Xf + (size_t)r * ldx + t * 8;
    float nrm = 0.f, dot = 0.f;
#pragma unroll
    for (int j = 0; j < 8; ++j) {
        float v = bf2f(p[j]);
        nrm = fmaf(v, v, nrm);
        dot = fmaf(xf[j], bc[t * 8 + j], dot);
    }
    for (int off = 32; off > 0; off >>= 1) {
        nrm += __shfl_down(nrm, off);
        dot += __shfl_down(dot, off);
    }
    if (t == 0) outv[r] = nrm - 2.f * dot;
}

__global__ void bcomb_k(const float* __restrict__ b_enc,
                        const float* __restrict__ W_key,
                        const float* __restrict__ b_key,
                        float* __restrict__ b_comb) {
    int h = blockIdx.x * 256 + threadIdx.x;
    if (h >= H_) return;
    float acc = b_key[h];
    for (int m = 0; m < H_; ++m)
        acc = fmaf(b_enc[m], W_key[(size_t)m * H_ + h], acc);
    b_comb[h] = acc;
}

// bq[h] = sum_m bc[m] * W1[m,h]
__global__ void bq_k(const float* __restrict__ bc,
                     const float* __restrict__ W1,
                     float* __restrict__ bq) {
    int h = blockIdx.x * 256 + threadIdx.x;
    if (h >= H_) return;
    float acc = 0.f;
    for (int m = 0; m < H_; ++m)
        acc = fmaf(bc[m], W1[(size_t)m * H_ + h], acc);
    bq[h] = acc;
}

__global__ __launch_bounds__(128) void softmax_k(const float* __restrict__ topVal,
                                                 float* __restrict__ attn) {
    __shared__ float red[128];
    const int b = blockIdx.x, t = threadIdx.x;
    float v = (t < K_) ? -sqrtf(topVal[b * K_ + t]) : -FLT_MAX;
    red[t] = v; __syncthreads();
    for (int s = 64; s > 0; s >>= 1) {
        if (t < s) red[t] = fmaxf(red[t], red[t + s]);
        __syncthreads();
    }
    float m = red[0]; __syncthreads();
    float e = (t < K_) ? expf(v - m) : 0.f;
    red[t] = e; __syncthreads();
    for (int s = 64; s > 0; s >>= 1) {
        if (t < s) red[t] += red[t + s];
        __syncthreads();
    }
    float ssum = red[0];
    if (t < K_) attn[b * K_ + t] = e / ssum;
}

// ---------------------------------------------------------------------------
// Stage-4 factorized: hw[b,:] = sum_k attn[b,k]*relu(P[b,:]-Q[topI[b,k],:]),
// P = xk@W1 + b1 (fp32), Q = cx@(Wc@W1) + bc@W1 (bf16, D-contraction).
// ---------------------------------------------------------------------------
__global__ __launch_bounds__(256) void wsum_q(const float* __restrict__ attn,
                                              const int* __restrict__ topI,
                                              const float* __restrict__ P,
                                              const ushort* __restrict__ Q,
                                              ushort* __restrict__ hw) {
    __shared__ float aw[K_];
    __shared__ int ai[K_];
    const int b = blockIdx.x, t = threadIdx.x;
    if (t < K_) { aw[t] = attn[b * K_ + t]; ai[t] = topI[b * K_ + t]; }
    __syncthreads();
    const float p0 = P[(size_t)b * H_ + 2 * t];
    const float p1 = P[(size_t)b * H_ + 2 * t + 1];
    float a0 = 0.f, a1 = 0.f;
    for (int k = 0; k < K_; ++k) {
        float w = aw[k];
        ushort2 q = *(const ushort2*)(Q + (size_t)ai[k] * H_ + 2 * t);
        a0 = fmaf(w, fmaxf(p0 - bf2f(q.x), 0.f), a0);
        a1 = fmaf(w, fmaxf(p1 - bf2f(q.y), 0.f), a1);
    }
    ushort2 o; o.x = f2bf(a0); o.y = f2bf(a1);
    *(ushort2*)(hw + (size_t)b * H_ + 2 * t) = o;
}

// out = xe + sum_k attn*E[label[topI]] + tsum   (xe = strided view of xekk)
__global__ __launch_bounds__(256) void final_out(const float* __restrict__ attn,
                                                 const int* __restrict__ topI,
                                                 const int* __restrict__ labels,
                                                 const float* __restrict__ E,
                                                 const float* __restrict__ tsum,
                                                 const float* __restrict__ xe,
                                                 int ldxe,
                                                 float* __restrict__ out) {
    const int b = blockIdx.x, t = threadIdx.x;
    float a0 = 0.f, a1 = 0.f;
    for (int k = 0; k < K_; ++k) {
        float w = attn[b * K_ + k];
        int idx = topI[b * K_ + k];
        int lab = labels[idx];
        const float* el = E + (size_t)lab * H_;
        a0 = fmaf(w, el[t], a0);
        a1 = fmaf(w, el[t + 256], a1);
    }
    out[(size_t)b * H_ + t] =
        xe[(size_t)b * ldxe + t] + a0 + tsum[(size_t)b * H_ + t];
    out[(size_t)b * H_ + t + 256] =
        xe[(size_t)b * ldxe + t + 256] + a1 + tsum[(size_t)b * H_ + t + 256];
}

// ---------------------------------------------------------------------------
extern "C" void kernel_launch(void* const* d_in, const int* in_sizes, int n_in,
                              void* d_out, int out_size, void* d_ws, size_t ws_size,
                              hipStream_t stream) {
    const float* x      = (const float*)d_in[0];
    const float* cx     = (const float*)d_in[1];
    const int*   labels = (const int*)d_in[2];
    const float* W_enc  = (const float*)d_in[3];
    const float* b_enc  = (const float*)d_in[4];
    const float* W_key  = (const float*)d_in[5];
    const float* b_key  = (const float*)d_in[6];
    // d_in[7]=W_val, d_in[8]=b_val dead (gather unused in reference)
    const float* E_label = (const float*)d_in[9];
    const float* W_t1   = (const float*)d_in[10];
    const float* b_t1   = (const float*)d_in[11];
    const float* W_t2   = (const float*)d_in[12];
    float* out = (float*)d_out;

    char* base = (char*)d_ws;
    size_t off = 0;
    auto take = [&](size_t n) -> char* {
        char* p = base + off;
        off = (off + n + 255) & ~(size_t)255;
        return p;
    };
    float*  Wc    = (float*)take((size_t)D_ * H_ * 4);
    float*  bc    = (float*)take((size_t)H_ * 4);
    float*  Wxx   = (float*)take((size_t)D_ * 1024 * 4);  // [W_enc | Wc] fp32
    float*  bxx   = (float*)take((size_t)1024 * 4);
    ushort* WcT   = (ushort*)take((size_t)H_ * D_ * 2);
    ushort* Wcb   = (ushort*)take((size_t)D_ * H_ * 2);   // Wc bf16 [D,H]
    float*  Wq    = (float*)take((size_t)D_ * H_ * 4);    // Wc @ W_t1, fp32
    ushort* WqT   = (ushort*)take((size_t)H_ * D_ * 2);   // Wq^T bf16 [H,D]
    float*  bq    = (float*)take((size_t)H_ * 4);         // bc @ W_t1
    ushort* Wt1T  = (ushort*)take((size_t)H_ * H_ * 2);
    ushort* Wt2T  = (ushort*)take((size_t)H_ * H_ * 2);
    float*  xekk  = (float*)take((size_t)B_ * 1024 * 4);  // [xe | xk] fp32
    ushort* xkb   = (ushort*)take((size_t)B_ * H_ * 2);
    ushort* xprojb= (ushort*)take((size_t)B_ * D_ * 2);   // xk @ Wc^T, bf16
    float*  q2x   = (float*)take((size_t)B_ * 4);
    float*  c2    = (float*)take((size_t)N_ * 4);
    float*  topV  = (float*)take((size_t)B_ * K_ * 4);
    int*    topI  = (int*)take((size_t)B_ * K_ * 4);
    float*  thr   = (float*)take((size_t)B_ * 4);
    float*  attn  = (float*)take((size_t)B_ * K_ * 4);
    int*    cnt   = (int*)take((size_t)B_ * 4);
    float*  candV = (float*)take((size_t)B_ * CAPC * 4);
    int*    candI = (int*)take((size_t)B_ * CAPC * 4);
    ushort* hwAll = (ushort*)take((size_t)B_ * H_ * 2);
    float*  tsum  = (float*)take((size_t)B_ * H_ * 4);
    float*  Pbuf  = (float*)take((size_t)B_ * H_ * 4);    // xk@W1+b1, fp32
    ushort* Qb    = (ushort*)take((size_t)N_ * H_ * 2);   // cx@Wq+bq, bf16
    char*   big   = base + off;

    ushort* cxb = (ushort*)big;       // N*D*2 = 51.2 MB
    float* simSmall = (float*)candV;  // B*SAMP*4 overlays candV (dead before 3b)

    const float* xeView = xekk;           // cols 0..511
    const float* xkView = xekk + 512;     // cols 512..1023 (stride 1024)

    // stage 0: combined weights + Q-weights + transposed bf16 weights
    {
        dim3 g(H_ / 64, D_ / 64);
        gemm_nn<0><<<g, 256, 0, stream>>>(W_enc, W_key, nullptr, Wc, D_, H_, H_);
        bcomb_k<<<(H_ + 255) / 256, 256, 0, stream>>>(b_enc, W_key, b_key, bc);
        gemm_nn<0><<<g, 256, 0, stream>>>(Wc, W_t1, nullptr, Wq, D_, H_, H_);
        bq_k<<<(H_ + 255) / 256, 256, 0, stream>>>(bc, W_t1, bq);
        pack_wxx<<<(D_ * H_ + 255) / 256, 256, 0, stream>>>(W_enc, Wc, b_enc,
                                                            bc, Wxx, bxx);
        dim3 gt1((H_ + 31) / 32, (D_ + 31) / 32);
        transpose_f2b<<<gt1, 256, 0, stream>>>(Wc, WcT, D_, H_);
        transpose_f2b<<<gt1, 256, 0, stream>>>(Wq, WqT, D_, H_);
        conv_f2b<<<128, 256, 0, stream>>>(Wc, Wcb, D_ * H_);
        dim3 gt2((H_ + 31) / 32, (H_ + 31) / 32);
        transpose_f2b<<<gt2, 256, 0, stream>>>(W_t1, Wt1T, H_, H_);
        transpose_f2b<<<gt2, 256, 0, stream>>>(W_t2, Wt2T, H_, H_);
    }
    // stage 1: fused query encodes [xe|xk] + bf16 conversions + xproj + P
    {
        dim3 gx(1024 / 64, B_ / 64);         // (16, 16) = 256 blocks
        gemm_nn<0><<<gx, 256, 0, stream>>>(x, Wxx, bxx, xekk, B_, 1024, D_);
        conv_f2b_s<<<1024, 256, 0, stream>>>(xkView, xkb, 1024);
        conv_f2b<<<2048, 256, 0, stream>>>(cx, cxb, N_ * D_);
        // xproj[B,D] = xkb @ Wcb^T (contract over H), bf16 out
        dim3 gp(D_ / 128, B_ / 128);         // (2, 8)
        gemm_nt<0, 0><<<gp, 256, 0, stream>>>(
            xkb, Wcb, nullptr, nullptr, nullptr, nullptr, nullptr, nullptr,
            nullptr, xprojb, B_, D_, H_, D_, D_, 0);
        q2x_k<<<B_, 64, 0, stream>>>(xkb, xkView, 1024, bc, q2x);
        // P[B,H] = xkb @ W_t1 + b_t1, fp32 out (MODE 4)
        dim3 gq(H_ / 128, B_ / 128);         // (4, 8)
        gemm_nt<4, 0><<<gq, 256, 0, stream>>>(
            xkb, Wt1T, b_t1, nullptr, nullptr, nullptr, nullptr, nullptr,
            nullptr, Pbuf, B_, H_, H_, H_, H_, 0);
    }
    // stage 2: candidate-key row norms c2 ONLY (MODE 7) -- ck values are
    // computed in-register and discarded; no 102MB ckb write, no rowsq pass.
    init_f32<<<128, 256, 0, stream>>>(c2, N_);
    {
        int mt = (N_ + 127) / 128;           // 782
        int mper = (mt + 7) / 8;             // 98
        gemm_nt<7, 2><<<8 * mper * 4, 256, 0, stream>>>(
            cxb, WcT, bc, nullptr, nullptr, nullptr, c2, nullptr, nullptr,
            nullptr, N_, H_, D_, H_, H_, mper);
    }
    // stage 3a: sample sim GEMM over D-contraction (first SAMP cols, raw dot)
    {
        int nper = (SAMP / 128 + 7) / 8;     // 4
        gemm_nt<2, 1><<<64 * nper, 256, 0, stream>>>(
            xprojb, cxb, nullptr, nullptr, nullptr, nullptr, nullptr, nullptr,
            nullptr, simSmall, B_, N_, D_, SAMP, SAMP, nper);
        thr_select<<<B_, 256, 0, stream>>>(simSmall, SAMP, q2x, c2, thr);
    }
    // stage 3b: fused sim GEMM (K=256) + in-epilogue threshold filter
    init_cnt<<<(B_ + 255) / 256, 256, 0, stream>>>(cnt);
    {
        int NT = (N_ + 127) / 128;           // 782
        int nper = (NT + 7) / 8;             // 98
        gemm_nt<5, 1><<<64 * nper, 256, 0, stream>>>(
            xprojb, cxb, nullptr, q2x, c2, thr, candV, candI, cnt,
            nullptr, B_, N_, D_, 0, N_, nper);
    }
    // Q[N,H] = cxb @ WqT^T + bq  (D-contraction: half the FLOPs of ck@W1)
    {
        int mt = (N_ + 127) / 128;           // 782
        int mper = (mt + 7) / 8;             // 98
        gemm_nt<3, 2><<<8 * mper * 4, 256, 0, stream>>>(
            cxb, WqT, bq, nullptr, nullptr, nullptr, nullptr, nullptr,
            nullptr, Qb, N_, H_, D_, H_, H_, mper);
    }
    final_select<<<B_, 256, 0, stream>>>(candV, candI, cnt, topV, topI);
    softmax_k<<<B_, 128, 0, stream>>>(topV, attn);

    // stage 4: hw = sum_k attn*relu(P-Q[topI]); tsum = hw@W2; out = ...
    wsum_q<<<B_, 256, 0, stream>>>(attn, topI, Pbuf, Qb, hwAll);
    {   // tsum[1024,512] = hwAll @ Wt2T^T (fp32 out via MODE 2)
        dim3 g(H_ / 128, B_ / 128);          // (4, 8)
        gemm_nt<2, 0><<<g, 256, 0, stream>>>(
            hwAll, Wt2T, nullptr, nullptr, nullptr, nullptr, nullptr, nullptr,
            nullptr, tsum, B_, H_, H_, H_, H_, 0);
    }
    final_out<<<B_, 256, 0, stream>>>(attn, topI, labels, E_label, tsum,
                                      xeView, 1024, out);
}